// Round 1
// baseline (429.628 us; speedup 1.0000x reference)
//
#include <hip/hip_runtime.h>

#define N_POS 9216
#define NCHUNK 9
#define CHUNKN 1024
#define BATCH 8
#define CDIM 64
#define HEADS 4
#define DHEAD 32
#define INNER 128
#define GROUPS 8
#define EPS 1e-5f

// ws layout (floats)
#define QKV_OFF 0
#define QKV_SZ (BATCH*384*N_POS)                      // 28311552
#define S_OFF  (QKV_OFF + QKV_SZ)
#define S_SZ   (BATCH*HEADS*NCHUNK*DHEAD*DHEAD)       // 294912
#define U_OFF  (S_OFF + S_SZ)
#define U_SZ   (BATCH*NCHUNK*INNER*CDIM)              // 589824
#define ST_OFF (U_OFF + U_SZ)
#define ST_SZ  (BATCH*GROUPS*2)                       // 128

__global__ void zero_stats_kernel(float* __restrict__ stats) {
    if (threadIdx.x < ST_SZ) stats[threadIdx.x] = 0.f;
}

// qkv[b][o][n] = sum_c Wqkv[o][c] * x[b][c][n]
__global__ __launch_bounds__(256) void qkv_kernel(const float* __restrict__ x,
        const float* __restrict__ Wqkv, float* __restrict__ qkv) {
    int tile = blockIdx.x;   // 36
    int sel  = blockIdx.y;   // 3
    int b    = blockIdx.z;   // 8
    int pos  = tile * 256 + threadIdx.x;
    const float* xb = x + (size_t)b * CDIM * N_POS + pos;
    float xr[CDIM];
    #pragma unroll
    for (int c = 0; c < CDIM; ++c) xr[c] = xb[(size_t)c * N_POS];
    const float* Wbase = Wqkv + sel * 128 * CDIM;     // uniform -> s_load path
    float* outp = qkv + ((size_t)b * 384 + sel * 128) * N_POS + pos;
    #pragma unroll 4
    for (int o = 0; o < 128; ++o) {
        const float* wrow = Wbase + o * CDIM;
        float acc = 0.f;
        #pragma unroll
        for (int c = 0; c < CDIM; ++c) acc += wrow[c] * xr[c];
        outp[(size_t)o * N_POS] = acc;
    }
}

// per (bh, chunk): S[d][d'] = sum_i softmax_i(q)[d][i] * softmax_d(k)[d'][i]
__global__ __launch_bounds__(256) void smat_kernel(const float* __restrict__ qkv,
        float* __restrict__ Smat) {
    int bh = blockIdx.x;   // 32
    int ck = blockIdx.y;   // 9
    int b = bh >> 2, h = bh & 3;
    int n0 = ck * CHUNKN;
    __shared__ float qsT[32][129];
    __shared__ float ksT[32][129];
    __shared__ float Mrow[32], iZrow[32];
    __shared__ float Sbuf[4][32][32];
    int t = threadIdx.x;
    int w = t >> 6, l = t & 63;
    const float* qbase = qkv + ((size_t)b * 384 + h * 32) * N_POS + n0;
    const float* kbase = qkv + ((size_t)b * 384 + 128 + h * 32) * N_POS + n0;
    // step 1: row max + exp-sum for q rows (wave w owns rows 8w..8w+7)
    for (int r = 0; r < 8; ++r) {
        int d = w * 8 + r;
        const float* qrow = qbase + (size_t)d * N_POS;
        float v[16];
        float mx = -1e30f;
        #pragma unroll
        for (int j = 0; j < 16; ++j) { v[j] = qrow[l + 64 * j]; mx = fmaxf(mx, v[j]); }
        #pragma unroll
        for (int off = 32; off >= 1; off >>= 1) mx = fmaxf(mx, __shfl_xor(mx, off, 64));
        float s = 0.f;
        #pragma unroll
        for (int j = 0; j < 16; ++j) s += __expf(v[j] - mx);
        #pragma unroll
        for (int off = 32; off >= 1; off >>= 1) s += __shfl_xor(s, off, 64);
        if (l == 0) { Mrow[d] = mx; iZrow[d] = 1.f / s; }
    }
    float acc[16];
    #pragma unroll
    for (int i = 0; i < 16; ++i) acc[i] = 0.f;
    int d0 = (l & 7) << 2, e0 = (l >> 3) << 2;
    for (int tile = 0; tile < 8; ++tile) {
        __syncthreads();
        int p = tile * 128 + (t & 127);
        if (t < 128) {
            // ks column: softmax over 32 channels at position p
            float kr[32]; float mx = -1e30f;
            #pragma unroll
            for (int d = 0; d < 32; ++d) { kr[d] = kbase[(size_t)d * N_POS + p]; mx = fmaxf(mx, kr[d]); }
            float s = 0.f;
            #pragma unroll
            for (int d = 0; d < 32; ++d) { kr[d] = __expf(kr[d] - mx); s += kr[d]; }
            float is = 1.f / s;
            #pragma unroll
            for (int d = 0; d < 32; ++d) ksT[d][t] = kr[d] * is;
        } else {
            int tc = t - 128;
            #pragma unroll
            for (int d = 0; d < 32; ++d) {
                float qv = qbase[(size_t)d * N_POS + p];
                qsT[d][tc] = __expf(qv - Mrow[d]) * iZrow[d];
            }
        }
        __syncthreads();
        // S += qsT * ksT^T over this tile; wave w covers kk quarter
        #pragma unroll 4
        for (int kk = w * 32; kk < w * 32 + 32; ++kk) {
            float qv[4], kv[4];
            #pragma unroll
            for (int j = 0; j < 4; ++j) { qv[j] = qsT[d0 + j][kk]; kv[j] = ksT[e0 + j][kk]; }
            #pragma unroll
            for (int j = 0; j < 4; ++j)
                #pragma unroll
                for (int jj = 0; jj < 4; ++jj) acc[j * 4 + jj] += qv[j] * kv[jj];
        }
    }
    __syncthreads();
    #pragma unroll
    for (int j = 0; j < 4; ++j)
        #pragma unroll
        for (int jj = 0; jj < 4; ++jj) Sbuf[w][d0 + j][e0 + jj] = acc[j * 4 + jj];
    __syncthreads();
    float* Sout = Smat + ((size_t)bh * NCHUNK + ck) * 1024;
    #pragma unroll
    for (int j = 0; j < 4; ++j) {
        int e = t * 4 + j;
        int d = e >> 5, dd = e & 31;
        Sout[e] = Sbuf[0][d][dd] + Sbuf[1][d][dd] + Sbuf[2][d][dd] + Sbuf[3][d][dd];
    }
}

// U[bk][c][o] = sum_d Wout[o][h*32+d] * S[b*4+h][ck][d][d'], c = h*32+d'
__global__ __launch_bounds__(256) void umat_kernel(const float* __restrict__ Wout,
        const float* __restrict__ Smat, float* __restrict__ U) {
    int ck = blockIdx.x; // 9
    int b  = blockIdx.y; // 8
    __shared__ float Wl[64][129];
    int t = threadIdx.x;
    for (int i = t; i < 64 * 128; i += 256) Wl[i >> 7][i & 127] = Wout[i];
    __syncthreads();
    int o = t & 63, hg = t >> 6;
    const float* S = Smat + ((size_t)(b * 4 + hg) * NCHUNK + ck) * 1024;  // wave-uniform
    float wrow[32];
    #pragma unroll
    for (int d = 0; d < 32; ++d) wrow[d] = Wl[o][hg * 32 + d];
    float* Ub = U + ((size_t)(b * NCHUNK + ck) * INNER + hg * 32) * 64 + o;
    for (int dd = 0; dd < 32; ++dd) {
        float acc = 0.f;
        #pragma unroll
        for (int d = 0; d < 32; ++d) acc += wrow[d] * S[d * 32 + dd];
        Ub[dd * 64] = acc;
    }
}

// y[b][o][pos] = b_out[o] + sum_c U[c][o]*v[c][pos]; fused GN stat accumulation
__global__ __launch_bounds__(256) void y_kernel(const float* __restrict__ qkv,
        const float* __restrict__ U, const float* __restrict__ bout,
        float* __restrict__ y, float* __restrict__ stats) {
    int pt = blockIdx.x;  // 4
    int ck = blockIdx.y;  // 9
    int b  = blockIdx.z;  // 8
    __shared__ __align__(16) float Ul[128][64];
    __shared__ float gsum[8], gsq[8];
    int t = threadIdx.x;
    const float* Ug = U + (size_t)(b * NCHUNK + ck) * INNER * 64;
    for (int i = t; i < 128 * 64; i += 256) ((float*)Ul)[i] = Ug[i];
    if (t < 8) { gsum[t] = 0.f; gsq[t] = 0.f; }
    __syncthreads();
    int pos = ck * CHUNKN + pt * 256 + t;
    const float* vbase = qkv + ((size_t)b * 384 + 256) * N_POS + pos;
    float acc[64];
    #pragma unroll
    for (int o = 0; o < 64; ++o) acc[o] = 0.f;
    for (int c = 0; c < 128; ++c) {
        float vv = vbase[(size_t)c * N_POS];
        const float4* urow = (const float4*)Ul[c];
        #pragma unroll
        for (int o4 = 0; o4 < 16; ++o4) {
            float4 u = urow[o4];
            acc[o4 * 4 + 0] += u.x * vv; acc[o4 * 4 + 1] += u.y * vv;
            acc[o4 * 4 + 2] += u.z * vv; acc[o4 * 4 + 3] += u.w * vv;
        }
    }
    float* yb = y + (size_t)b * CDIM * N_POS + pos;
    float gs[8], gq[8];
    #pragma unroll
    for (int g = 0; g < 8; ++g) { gs[g] = 0.f; gq[g] = 0.f; }
    #pragma unroll
    for (int o = 0; o < 64; ++o) {
        float val = acc[o] + bout[o];
        yb[(size_t)o * N_POS] = val;
        gs[o >> 3] += val; gq[o >> 3] += val * val;
    }
    #pragma unroll
    for (int g = 0; g < 8; ++g) {
        #pragma unroll
        for (int off = 32; off >= 1; off >>= 1) {
            gs[g] += __shfl_xor(gs[g], off, 64);
            gq[g] += __shfl_xor(gq[g], off, 64);
        }
    }
    if ((t & 63) == 0) {
        #pragma unroll
        for (int g = 0; g < 8; ++g) { atomicAdd(&gsum[g], gs[g]); atomicAdd(&gsq[g], gq[g]); }
    }
    __syncthreads();
    if (t < 8) {
        atomicAdd(&stats[(b * 8 + t) * 2],     gsum[t]);
        atomicAdd(&stats[(b * 8 + t) * 2 + 1], gsq[t]);
    }
}

__global__ __launch_bounds__(256) void gn_kernel(float* __restrict__ y,
        const float* __restrict__ stats, const float* __restrict__ gamma,
        const float* __restrict__ beta) {
    int i4 = blockIdx.x * 256 + threadIdx.x;
    if (i4 >= (BATCH * CDIM * N_POS) / 4) return;
    int base = i4 * 4;
    int bc = base / N_POS;
    int c = bc & 63, b = bc >> 6;
    int g = c >> 3;
    float s = stats[(b * 8 + g) * 2], q = stats[(b * 8 + g) * 2 + 1];
    const float invN = 1.f / (8.f * N_POS);
    float mean = s * invN;
    float var = q * invN - mean * mean;
    float sc = rsqrtf(var + EPS);
    float ga = gamma[c] * sc;
    float be = beta[c] - mean * sc * gamma[c];
    float4 v = ((float4*)y)[i4];
    v.x = v.x * ga + be; v.y = v.y * ga + be; v.z = v.z * ga + be; v.w = v.w * ga + be;
    ((float4*)y)[i4] = v;
}

extern "C" void kernel_launch(void* const* d_in, const int* in_sizes, int n_in,
                              void* d_out, int out_size, void* d_ws, size_t ws_size,
                              hipStream_t stream) {
    const float* x     = (const float*)d_in[0];
    const float* Wqkv  = (const float*)d_in[1];
    const float* Wout  = (const float*)d_in[2];
    const float* bout  = (const float*)d_in[3];
    const float* gamma = (const float*)d_in[4];
    const float* beta  = (const float*)d_in[5];
    float* out = (float*)d_out;
    float* ws  = (float*)d_ws;

    float* qkv   = ws + QKV_OFF;
    float* Smat  = ws + S_OFF;
    float* U     = ws + U_OFF;
    float* stats = ws + ST_OFF;

    zero_stats_kernel<<<1, 128, 0, stream>>>(stats);
    qkv_kernel<<<dim3(36, 3, BATCH), 256, 0, stream>>>(x, Wqkv, qkv);
    smat_kernel<<<dim3(32, NCHUNK), 256, 0, stream>>>(qkv, Smat);
    umat_kernel<<<dim3(NCHUNK, BATCH), 256, 0, stream>>>(Wout, Smat, U);
    y_kernel<<<dim3(4, NCHUNK, BATCH), 256, 0, stream>>>(qkv, U, bout, out, stats);
    gn_kernel<<<dim3((BATCH * CDIM * N_POS / 4 + 255) / 256), 256, 0, stream>>>(out, stats, gamma, beta);
}

// Round 2
// 345.568 us; speedup vs baseline: 1.2433x; 1.2433x over previous
//
#include <hip/hip_runtime.h>
#include <hip/hip_bf16.h>

#define N_POS 9216
#define NCHUNK 9
#define CHUNKN 1024
#define BATCH 8
#define CDIM 64
#define HEADS 4
#define DHEAD 32
#define INNER 128
#define GROUPS 8
#define EPS 1e-5f

// ws layout: bf16 qkv first, then float region
#define QKV_SZ (BATCH*384*N_POS)                      // 28311552 bf16 elems
#define QKV_BYTES ((size_t)QKV_SZ * 2)
#define S_OFF  0
#define S_SZ   (BATCH*HEADS*NCHUNK*DHEAD*DHEAD)       // 294912
#define U_OFF  (S_OFF + S_SZ)
#define U_SZ   (BATCH*NCHUNK*INNER*CDIM)              // 589824
#define ST_OFF (U_OFF + U_SZ)
#define ST_SZ  (BATCH*GROUPS*2)                       // 128

__global__ void zero_stats_kernel(float* __restrict__ stats) {
    if (threadIdx.x < ST_SZ) stats[threadIdx.x] = 0.f;
}

// qkv[b][o][n] = sum_c Wqkv[o][c] * x[b][c][n]  (bf16 out)
// grid (36, 12, 8): each thread computes 1 position x 32 outputs
__global__ __launch_bounds__(256) void qkv_kernel(const float* __restrict__ x,
        const float* __restrict__ Wqkv, __hip_bfloat16* __restrict__ qkv) {
    int tile = blockIdx.x;   // 36
    int og   = blockIdx.y;   // 12 (32 outputs each)
    int b    = blockIdx.z;   // 8
    int pos  = tile * 256 + threadIdx.x;
    const float* xb = x + (size_t)b * CDIM * N_POS + pos;
    float xr[CDIM];
    #pragma unroll
    for (int c = 0; c < CDIM; ++c) xr[c] = xb[(size_t)c * N_POS];
    const float* Wbase = Wqkv + og * 32 * CDIM;       // wave-uniform
    __hip_bfloat16* outp = qkv + ((size_t)b * 384 + og * 32) * N_POS + pos;
    #pragma unroll 4
    for (int o = 0; o < 32; ++o) {
        const float* wrow = Wbase + o * CDIM;
        float acc = 0.f;
        #pragma unroll
        for (int c = 0; c < CDIM; ++c) acc += wrow[c] * xr[c];
        outp[(size_t)o * N_POS] = __float2bfloat16(acc);
    }
}

// per (bh, chunk): S[d][d'] = sum_i softmax_i(q)[d][i] * softmax_d(k)[d'][i]
__global__ __launch_bounds__(256) void smat_kernel(const __hip_bfloat16* __restrict__ qkv,
        float* __restrict__ Smat) {
    int bh = blockIdx.x;   // 32
    int ck = blockIdx.y;   // 9
    int b = bh >> 2, h = bh & 3;
    int n0 = ck * CHUNKN;
    __shared__ float qsT[32][129];
    __shared__ float ksT[32][129];
    __shared__ float Mrow[32], iZrow[32];
    __shared__ float Sbuf[4][32][32];
    int t = threadIdx.x;
    int w = t >> 6, l = t & 63;
    const __hip_bfloat16* qbase = qkv + ((size_t)b * 384 + h * 32) * N_POS + n0;
    const __hip_bfloat16* kbase = qkv + ((size_t)b * 384 + 128 + h * 32) * N_POS + n0;
    // step 1: row max + exp-sum for q rows (wave w owns rows 8w..8w+7)
    for (int r = 0; r < 8; ++r) {
        int d = w * 8 + r;
        const __hip_bfloat16* qrow = qbase + (size_t)d * N_POS;
        float v[16];
        float mx = -1e30f;
        #pragma unroll
        for (int j = 0; j < 16; ++j) { v[j] = __bfloat162float(qrow[l + 64 * j]); mx = fmaxf(mx, v[j]); }
        #pragma unroll
        for (int off = 32; off >= 1; off >>= 1) mx = fmaxf(mx, __shfl_xor(mx, off, 64));
        float s = 0.f;
        #pragma unroll
        for (int j = 0; j < 16; ++j) s += __expf(v[j] - mx);
        #pragma unroll
        for (int off = 32; off >= 1; off >>= 1) s += __shfl_xor(s, off, 64);
        if (l == 0) { Mrow[d] = mx; iZrow[d] = 1.f / s; }
    }
    float acc[16];
    #pragma unroll
    for (int i = 0; i < 16; ++i) acc[i] = 0.f;
    int d0 = (l & 7) << 2, e0 = (l >> 3) << 2;
    for (int tile = 0; tile < 8; ++tile) {
        __syncthreads();
        int p = tile * 128 + (t & 127);
        if (t < 128) {
            // ks column: softmax over 32 channels at position p
            float kr[32]; float mx = -1e30f;
            #pragma unroll
            for (int d = 0; d < 32; ++d) { kr[d] = __bfloat162float(kbase[(size_t)d * N_POS + p]); mx = fmaxf(mx, kr[d]); }
            float s = 0.f;
            #pragma unroll
            for (int d = 0; d < 32; ++d) { kr[d] = __expf(kr[d] - mx); s += kr[d]; }
            float is = 1.f / s;
            #pragma unroll
            for (int d = 0; d < 32; ++d) ksT[d][t] = kr[d] * is;
        } else {
            int tc = t - 128;
            #pragma unroll
            for (int d = 0; d < 32; ++d) {
                float qv = __bfloat162float(qbase[(size_t)d * N_POS + p]);
                qsT[d][tc] = __expf(qv - Mrow[d]) * iZrow[d];
            }
        }
        __syncthreads();
        // S += qsT * ksT^T over this tile; wave w covers kk quarter
        #pragma unroll 4
        for (int kk = w * 32; kk < w * 32 + 32; ++kk) {
            float qv[4], kv[4];
            #pragma unroll
            for (int j = 0; j < 4; ++j) { qv[j] = qsT[d0 + j][kk]; kv[j] = ksT[e0 + j][kk]; }
            #pragma unroll
            for (int j = 0; j < 4; ++j)
                #pragma unroll
                for (int jj = 0; jj < 4; ++jj) acc[j * 4 + jj] += qv[j] * kv[jj];
        }
    }
    __syncthreads();
    #pragma unroll
    for (int j = 0; j < 4; ++j)
        #pragma unroll
        for (int jj = 0; jj < 4; ++jj) Sbuf[w][d0 + j][e0 + jj] = acc[j * 4 + jj];
    __syncthreads();
    float* Sout = Smat + ((size_t)bh * NCHUNK + ck) * 1024;
    #pragma unroll
    for (int j = 0; j < 4; ++j) {
        int e = t * 4 + j;
        int d = e >> 5, dd = e & 31;
        Sout[e] = Sbuf[0][d][dd] + Sbuf[1][d][dd] + Sbuf[2][d][dd] + Sbuf[3][d][dd];
    }
}

// U[bk][c][o] = sum_d Wout[o][h*32+d] * S[b*4+h][ck][d][d'], c = h*32+d'
__global__ __launch_bounds__(256) void umat_kernel(const float* __restrict__ Wout,
        const float* __restrict__ Smat, float* __restrict__ U) {
    int ck = blockIdx.x; // 9
    int b  = blockIdx.y; // 8
    __shared__ float Wl[64][129];
    int t = threadIdx.x;
    for (int i = t; i < 64 * 128; i += 256) Wl[i >> 7][i & 127] = Wout[i];
    __syncthreads();
    int o = t & 63, hg = t >> 6;
    const float* S = Smat + ((size_t)(b * 4 + hg) * NCHUNK + ck) * 1024;  // wave-uniform
    float wrow[32];
    #pragma unroll
    for (int d = 0; d < 32; ++d) wrow[d] = Wl[o][hg * 32 + d];
    float* Ub = U + ((size_t)(b * NCHUNK + ck) * INNER + hg * 32) * 64 + o;
    for (int dd = 0; dd < 32; ++dd) {
        float acc = 0.f;
        #pragma unroll
        for (int d = 0; d < 32; ++d) acc += wrow[d] * S[d * 32 + dd];
        Ub[dd * 64] = acc;
    }
}

// y[b][o][pos] = b_out[o] + sum_c U[c][o]*v[c][pos]; fused GN stat accumulation
__global__ __launch_bounds__(256) void y_kernel(const __hip_bfloat16* __restrict__ qkv,
        const float* __restrict__ U, const float* __restrict__ bout,
        float* __restrict__ y, float* __restrict__ stats) {
    int pt = blockIdx.x;  // 4
    int ck = blockIdx.y;  // 9
    int b  = blockIdx.z;  // 8
    __shared__ __align__(16) float Ul[128][64];
    __shared__ float gsum[8], gsq[8];
    int t = threadIdx.x;
    const float* Ug = U + (size_t)(b * NCHUNK + ck) * INNER * 64;
    for (int i = t; i < 128 * 64; i += 256) ((float*)Ul)[i] = Ug[i];
    if (t < 8) { gsum[t] = 0.f; gsq[t] = 0.f; }
    __syncthreads();
    int pos = ck * CHUNKN + pt * 256 + t;
    const __hip_bfloat16* vbase = qkv + ((size_t)b * 384 + 256) * N_POS + pos;
    float acc[64];
    #pragma unroll
    for (int o = 0; o < 64; ++o) acc[o] = 0.f;
    for (int c = 0; c < 128; ++c) {
        float vv = __bfloat162float(vbase[(size_t)c * N_POS]);
        const float4* urow = (const float4*)Ul[c];
        #pragma unroll
        for (int o4 = 0; o4 < 16; ++o4) {
            float4 u = urow[o4];
            acc[o4 * 4 + 0] += u.x * vv; acc[o4 * 4 + 1] += u.y * vv;
            acc[o4 * 4 + 2] += u.z * vv; acc[o4 * 4 + 3] += u.w * vv;
        }
    }
    float* yb = y + (size_t)b * CDIM * N_POS + pos;
    float gs[8], gq[8];
    #pragma unroll
    for (int g = 0; g < 8; ++g) { gs[g] = 0.f; gq[g] = 0.f; }
    #pragma unroll
    for (int o = 0; o < 64; ++o) {
        float val = acc[o] + bout[o];
        yb[(size_t)o * N_POS] = val;
        gs[o >> 3] += val; gq[o >> 3] += val * val;
    }
    #pragma unroll
    for (int g = 0; g < 8; ++g) {
        #pragma unroll
        for (int off = 32; off >= 1; off >>= 1) {
            gs[g] += __shfl_xor(gs[g], off, 64);
            gq[g] += __shfl_xor(gq[g], off, 64);
        }
    }
    if ((t & 63) == 0) {
        #pragma unroll
        for (int g = 0; g < 8; ++g) { atomicAdd(&gsum[g], gs[g]); atomicAdd(&gsq[g], gq[g]); }
    }
    __syncthreads();
    if (t < 8) {
        atomicAdd(&stats[(b * 8 + t) * 2],     gsum[t]);
        atomicAdd(&stats[(b * 8 + t) * 2 + 1], gsq[t]);
    }
}

__global__ __launch_bounds__(256) void gn_kernel(float* __restrict__ y,
        const float* __restrict__ stats, const float* __restrict__ gamma,
        const float* __restrict__ beta) {
    int i4 = blockIdx.x * 256 + threadIdx.x;
    if (i4 >= (BATCH * CDIM * N_POS) / 4) return;
    int base = i4 * 4;
    int bc = base / N_POS;
    int c = bc & 63, b = bc >> 6;
    int g = c >> 3;
    float s = stats[(b * 8 + g) * 2], q = stats[(b * 8 + g) * 2 + 1];
    const float invN = 1.f / (8.f * N_POS);
    float mean = s * invN;
    float var = q * invN - mean * mean;
    float sc = rsqrtf(var + EPS);
    float ga = gamma[c] * sc;
    float be = beta[c] - mean * sc * gamma[c];
    float4 v = ((float4*)y)[i4];
    v.x = v.x * ga + be; v.y = v.y * ga + be; v.z = v.z * ga + be; v.w = v.w * ga + be;
    ((float4*)y)[i4] = v;
}

extern "C" void kernel_launch(void* const* d_in, const int* in_sizes, int n_in,
                              void* d_out, int out_size, void* d_ws, size_t ws_size,
                              hipStream_t stream) {
    const float* x     = (const float*)d_in[0];
    const float* Wqkv  = (const float*)d_in[1];
    const float* Wout  = (const float*)d_in[2];
    const float* bout  = (const float*)d_in[3];
    const float* gamma = (const float*)d_in[4];
    const float* beta  = (const float*)d_in[5];
    float* out = (float*)d_out;

    __hip_bfloat16* qkv = (__hip_bfloat16*)d_ws;
    float* fbase = (float*)((char*)d_ws + QKV_BYTES);
    float* Smat  = fbase + S_OFF;
    float* U     = fbase + U_OFF;
    float* stats = fbase + ST_OFF;

    zero_stats_kernel<<<1, 128, 0, stream>>>(stats);
    qkv_kernel<<<dim3(36, 12, BATCH), 256, 0, stream>>>(x, Wqkv, qkv);
    smat_kernel<<<dim3(32, NCHUNK), 256, 0, stream>>>(qkv, Smat);
    umat_kernel<<<dim3(NCHUNK, BATCH), 256, 0, stream>>>(Wout, Smat, U);
    y_kernel<<<dim3(4, NCHUNK, BATCH), 256, 0, stream>>>(qkv, U, bout, out, stats);
    gn_kernel<<<dim3((BATCH * CDIM * N_POS / 4 + 255) / 256), 256, 0, stream>>>(out, stats, gamma, beta);
}

// Round 3
// 215.017 us; speedup vs baseline: 1.9981x; 1.6072x over previous
//
#include <hip/hip_runtime.h>
#include <hip/hip_bf16.h>

#define N_POS 9216
#define NCHUNK 9
#define CHUNKN 1024
#define BATCH 8
#define CDIM 64
#define HEADS 4
#define DHEAD 32
#define INNER 128
#define GROUPS 8
#define EPS 1e-5f

// ws layout: bf16 qkv first, then float region
#define QKV_SZ (BATCH*384*N_POS)                      // 28311552 bf16 elems
#define QKV_BYTES ((size_t)QKV_SZ * 2)
#define S_OFF  0
#define S_SZ   (BATCH*HEADS*NCHUNK*DHEAD*DHEAD)       // 294912
#define U_OFF  (S_OFF + S_SZ)
#define U_SZ   (BATCH*NCHUNK*INNER*CDIM)              // 589824
#define ST_OFF (U_OFF + U_SZ)
#define ST_SZ  (BATCH*GROUPS*2)                       // 128

typedef __attribute__((ext_vector_type(8))) short short8;
typedef __attribute__((ext_vector_type(4))) float f32x4;

static __device__ inline unsigned pk2(float a, float b) {
    __hip_bfloat162 h2(__float2bfloat16(a), __float2bfloat16(b));
    return *reinterpret_cast<unsigned*>(&h2);
}

__global__ void zero_stats_kernel(float* __restrict__ stats) {
    if (threadIdx.x < ST_SZ) stats[threadIdx.x] = 0.f;
}

// qkv[b][o][n] = sum_c Wqkv[o][c] * x[b][c][n]  via bf16 MFMA.
// grid (36, 3, 8); block 256 = 4 waves; tile BM=128, BN=256, K=64.
__global__ __launch_bounds__(256) void qkv_kernel(const float* __restrict__ x,
        const float* __restrict__ Wqkv, __hip_bfloat16* __restrict__ qkv) {
    int n0 = blockIdx.x * 256;
    int m0 = blockIdx.y * 128;
    int b  = blockIdx.z;
    __shared__ __hip_bfloat16 xs[256][72];   // [n][k], pad to 72
    __shared__ __hip_bfloat16 wsm[128][72];  // [m][k], pad to 72
    int t = threadIdx.x;
    int w = t >> 6, l = t & 63;

    // stage x tile: thread t owns position n0+t, packs 4 c's per b64 write
    {
        const float* xb = x + (size_t)b * CDIM * N_POS + n0 + t;
        #pragma unroll
        for (int c = 0; c < 64; c += 4) {
            float v0 = xb[(size_t)(c + 0) * N_POS];
            float v1 = xb[(size_t)(c + 1) * N_POS];
            float v2 = xb[(size_t)(c + 2) * N_POS];
            float v3 = xb[(size_t)(c + 3) * N_POS];
            uint2 u; u.x = pk2(v0, v1); u.y = pk2(v2, v3);
            *reinterpret_cast<uint2*>(&xs[t][c]) = u;
        }
    }
    // stage W tile: thread t -> row m0 + t/2, half (t&1) of 64 c's
    {
        int m = t >> 1, ch = (t & 1) * 32;
        const float4* wr = (const float4*)(Wqkv + (size_t)(m0 + m) * CDIM + ch);
        #pragma unroll
        for (int j = 0; j < 8; ++j) {
            float4 v = wr[j];
            uint2 u; u.x = pk2(v.x, v.y); u.y = pk2(v.z, v.w);
            *reinterpret_cast<uint2*>(&wsm[m][ch + j * 4]) = u;
        }
    }
    __syncthreads();

    int lrow = l & 15, lquad = l >> 4;
    f32x4 acc[8][4];
    #pragma unroll
    for (int mt = 0; mt < 8; ++mt)
        #pragma unroll
        for (int nt = 0; nt < 4; ++nt) acc[mt][nt] = (f32x4){0.f, 0.f, 0.f, 0.f};

    #pragma unroll
    for (int ks = 0; ks < 2; ++ks) {
        int k0 = lquad * 8 + ks * 32;
        short8 bfr[4];
        #pragma unroll
        for (int nt = 0; nt < 4; ++nt) {
            int n = w * 64 + nt * 16 + lrow;
            bfr[nt] = *reinterpret_cast<const short8*>(&xs[n][k0]);
        }
        #pragma unroll
        for (int mt = 0; mt < 8; ++mt) {
            short8 afr = *reinterpret_cast<const short8*>(&wsm[mt * 16 + lrow][k0]);
            #pragma unroll
            for (int nt = 0; nt < 4; ++nt)
                acc[mt][nt] = __builtin_amdgcn_mfma_f32_16x16x32_bf16(afr, bfr[nt], acc[mt][nt], 0, 0, 0);
        }
    }

    // epilogue: D[row=lquad*4+r][col=lrow] per 16x16 tile
    __hip_bfloat16* outp = qkv + ((size_t)b * 384 + m0) * N_POS + n0;
    #pragma unroll
    for (int mt = 0; mt < 8; ++mt)
        #pragma unroll
        for (int nt = 0; nt < 4; ++nt) {
            int n = w * 64 + nt * 16 + lrow;
            #pragma unroll
            for (int r = 0; r < 4; ++r) {
                int o = mt * 16 + lquad * 4 + r;
                outp[(size_t)o * N_POS + n] = __float2bfloat16(acc[mt][nt][r]);
            }
        }
}

// per (bh, chunk): S[d][d'] = sum_i softmax_i(q)[d][i] * softmax_d(k)[d'][i]
__global__ __launch_bounds__(256) void smat_kernel(const __hip_bfloat16* __restrict__ qkv,
        float* __restrict__ Smat) {
    int bh = blockIdx.x;   // 32
    int ck = blockIdx.y;   // 9
    int b = bh >> 2, h = bh & 3;
    int n0 = ck * CHUNKN;
    __shared__ float qsT[32][129];
    __shared__ float ksT[32][129];
    __shared__ float Mrow[32], iZrow[32];
    __shared__ float Sbuf[4][32][32];
    int t = threadIdx.x;
    int w = t >> 6, l = t & 63;
    const __hip_bfloat16* qbase = qkv + ((size_t)b * 384 + h * 32) * N_POS + n0;
    const __hip_bfloat16* kbase = qkv + ((size_t)b * 384 + 128 + h * 32) * N_POS + n0;
    for (int r = 0; r < 8; ++r) {
        int d = w * 8 + r;
        const __hip_bfloat16* qrow = qbase + (size_t)d * N_POS;
        float v[16];
        float mx = -1e30f;
        #pragma unroll
        for (int j = 0; j < 16; ++j) { v[j] = __bfloat162float(qrow[l + 64 * j]); mx = fmaxf(mx, v[j]); }
        #pragma unroll
        for (int off = 32; off >= 1; off >>= 1) mx = fmaxf(mx, __shfl_xor(mx, off, 64));
        float s = 0.f;
        #pragma unroll
        for (int j = 0; j < 16; ++j) s += __expf(v[j] - mx);
        #pragma unroll
        for (int off = 32; off >= 1; off >>= 1) s += __shfl_xor(s, off, 64);
        if (l == 0) { Mrow[d] = mx; iZrow[d] = 1.f / s; }
    }
    float acc[16];
    #pragma unroll
    for (int i = 0; i < 16; ++i) acc[i] = 0.f;
    int d0 = (l & 7) << 2, e0 = (l >> 3) << 2;
    for (int tile = 0; tile < 8; ++tile) {
        __syncthreads();
        int p = tile * 128 + (t & 127);
        if (t < 128) {
            float kr[32]; float mx = -1e30f;
            #pragma unroll
            for (int d = 0; d < 32; ++d) { kr[d] = __bfloat162float(kbase[(size_t)d * N_POS + p]); mx = fmaxf(mx, kr[d]); }
            float s = 0.f;
            #pragma unroll
            for (int d = 0; d < 32; ++d) { kr[d] = __expf(kr[d] - mx); s += kr[d]; }
            float is = 1.f / s;
            #pragma unroll
            for (int d = 0; d < 32; ++d) ksT[d][t] = kr[d] * is;
        } else {
            int tc = t - 128;
            #pragma unroll
            for (int d = 0; d < 32; ++d) {
                float qv = __bfloat162float(qbase[(size_t)d * N_POS + p]);
                qsT[d][tc] = __expf(qv - Mrow[d]) * iZrow[d];
            }
        }
        __syncthreads();
        #pragma unroll 4
        for (int kk = w * 32; kk < w * 32 + 32; ++kk) {
            float qv[4], kv[4];
            #pragma unroll
            for (int j = 0; j < 4; ++j) { qv[j] = qsT[d0 + j][kk]; kv[j] = ksT[e0 + j][kk]; }
            #pragma unroll
            for (int j = 0; j < 4; ++j)
                #pragma unroll
                for (int jj = 0; jj < 4; ++jj) acc[j * 4 + jj] += qv[j] * kv[jj];
        }
    }
    __syncthreads();
    #pragma unroll
    for (int j = 0; j < 4; ++j)
        #pragma unroll
        for (int jj = 0; jj < 4; ++jj) Sbuf[w][d0 + j][e0 + jj] = acc[j * 4 + jj];
    __syncthreads();
    float* Sout = Smat + ((size_t)bh * NCHUNK + ck) * 1024;
    #pragma unroll
    for (int j = 0; j < 4; ++j) {
        int e = t * 4 + j;
        int d = e >> 5, dd = e & 31;
        Sout[e] = Sbuf[0][d][dd] + Sbuf[1][d][dd] + Sbuf[2][d][dd] + Sbuf[3][d][dd];
    }
}

// U[bk][c][o] = sum_d Wout[o][h*32+d] * S[b*4+h][ck][d][d'], c = h*32+d'
__global__ __launch_bounds__(256) void umat_kernel(const float* __restrict__ Wout,
        const float* __restrict__ Smat, float* __restrict__ U) {
    int ck = blockIdx.x; // 9
    int b  = blockIdx.y; // 8
    __shared__ float Wl[64][129];
    int t = threadIdx.x;
    for (int i = t; i < 64 * 128; i += 256) Wl[i >> 7][i & 127] = Wout[i];
    __syncthreads();
    int o = t & 63, hg = t >> 6;
    const float* S = Smat + ((size_t)(b * 4 + hg) * NCHUNK + ck) * 1024;
    float wrow[32];
    #pragma unroll
    for (int d = 0; d < 32; ++d) wrow[d] = Wl[o][hg * 32 + d];
    float* Ub = U + ((size_t)(b * NCHUNK + ck) * INNER + hg * 32) * 64 + o;
    for (int dd = 0; dd < 32; ++dd) {
        float acc = 0.f;
        #pragma unroll
        for (int d = 0; d < 32; ++d) acc += wrow[d] * S[d * 32 + dd];
        Ub[dd * 64] = acc;
    }
}

// y[b][o][pos] = b_out[o] + sum_c U[c][o]*v[c][pos]; fused GN stat accumulation
__global__ __launch_bounds__(256) void y_kernel(const __hip_bfloat16* __restrict__ qkv,
        const float* __restrict__ U, const float* __restrict__ bout,
        float* __restrict__ y, float* __restrict__ stats) {
    int pt = blockIdx.x;  // 4
    int ck = blockIdx.y;  // 9
    int b  = blockIdx.z;  // 8
    __shared__ __align__(16) float Ul[128][64];
    __shared__ float gsum[8], gsq[8];
    int t = threadIdx.x;
    const float* Ug = U + (size_t)(b * NCHUNK + ck) * INNER * 64;
    for (int i = t; i < 128 * 64; i += 256) ((float*)Ul)[i] = Ug[i];
    if (t < 8) { gsum[t] = 0.f; gsq[t] = 0.f; }
    __syncthreads();
    int pos = ck * CHUNKN + pt * 256 + t;
    const __hip_bfloat16* vbase = qkv + ((size_t)b * 384 + 256) * N_POS + pos;
    float acc[64];
    #pragma unroll
    for (int o = 0; o < 64; ++o) acc[o] = 0.f;
    for (int c = 0; c < 128; ++c) {
        float vv = __bfloat162float(vbase[(size_t)c * N_POS]);
        const float4* urow = (const float4*)Ul[c];
        #pragma unroll
        for (int o4 = 0; o4 < 16; ++o4) {
            float4 u = urow[o4];
            acc[o4 * 4 + 0] += u.x * vv; acc[o4 * 4 + 1] += u.y * vv;
            acc[o4 * 4 + 2] += u.z * vv; acc[o4 * 4 + 3] += u.w * vv;
        }
    }
    float* yb = y + (size_t)b * CDIM * N_POS + pos;
    float gs[8], gq[8];
    #pragma unroll
    for (int g = 0; g < 8; ++g) { gs[g] = 0.f; gq[g] = 0.f; }
    #pragma unroll
    for (int o = 0; o < 64; ++o) {
        float val = acc[o] + bout[o];
        yb[(size_t)o * N_POS] = val;
        gs[o >> 3] += val; gq[o >> 3] += val * val;
    }
    #pragma unroll
    for (int g = 0; g < 8; ++g) {
        #pragma unroll
        for (int off = 32; off >= 1; off >>= 1) {
            gs[g] += __shfl_xor(gs[g], off, 64);
            gq[g] += __shfl_xor(gq[g], off, 64);
        }
    }
    if ((t & 63) == 0) {
        #pragma unroll
        for (int g = 0; g < 8; ++g) { atomicAdd(&gsum[g], gs[g]); atomicAdd(&gsq[g], gq[g]); }
    }
    __syncthreads();
    if (t < 8) {
        atomicAdd(&stats[(b * 8 + t) * 2],     gsum[t]);
        atomicAdd(&stats[(b * 8 + t) * 2 + 1], gsq[t]);
    }
}

__global__ __launch_bounds__(256) void gn_kernel(float* __restrict__ y,
        const float* __restrict__ stats, const float* __restrict__ gamma,
        const float* __restrict__ beta) {
    int i4 = blockIdx.x * 256 + threadIdx.x;
    if (i4 >= (BATCH * CDIM * N_POS) / 4) return;
    int base = i4 * 4;
    int bc = base / N_POS;
    int c = bc & 63, b = bc >> 6;
    int g = c >> 3;
    float s = stats[(b * 8 + g) * 2], q = stats[(b * 8 + g) * 2 + 1];
    const float invN = 1.f / (8.f * N_POS);
    float mean = s * invN;
    float var = q * invN - mean * mean;
    float sc = rsqrtf(var + EPS);
    float ga = gamma[c] * sc;
    float be = beta[c] - mean * sc * gamma[c];
    float4 v = ((float4*)y)[i4];
    v.x = v.x * ga + be; v.y = v.y * ga + be; v.z = v.z * ga + be; v.w = v.w * ga + be;
    ((float4*)y)[i4] = v;
}

extern "C" void kernel_launch(void* const* d_in, const int* in_sizes, int n_in,
                              void* d_out, int out_size, void* d_ws, size_t ws_size,
                              hipStream_t stream) {
    const float* x     = (const float*)d_in[0];
    const float* Wqkv  = (const float*)d_in[1];
    const float* Wout  = (const float*)d_in[2];
    const float* bout  = (const float*)d_in[3];
    const float* gamma = (const float*)d_in[4];
    const float* beta  = (const float*)d_in[5];
    float* out = (float*)d_out;

    __hip_bfloat16* qkv = (__hip_bfloat16*)d_ws;
    float* fbase = (float*)((char*)d_ws + QKV_BYTES);
    float* Smat  = fbase + S_OFF;
    float* U     = fbase + U_OFF;
    float* stats = fbase + ST_OFF;

    zero_stats_kernel<<<1, 128, 0, stream>>>(stats);
    qkv_kernel<<<dim3(36, 3, BATCH), 256, 0, stream>>>(x, Wqkv, qkv);
    smat_kernel<<<dim3(32, NCHUNK), 256, 0, stream>>>(qkv, Smat);
    umat_kernel<<<dim3(NCHUNK, BATCH), 256, 0, stream>>>(Wout, Smat, U);
    y_kernel<<<dim3(4, NCHUNK, BATCH), 256, 0, stream>>>(qkv, U, bout, out, stats);
    gn_kernel<<<dim3((BATCH * CDIM * N_POS / 4 + 255) / 256), 256, 0, stream>>>(out, stats, gamma, beta);
}

// Round 4
// 166.811 us; speedup vs baseline: 2.5755x; 1.2890x over previous
//
#include <hip/hip_runtime.h>
#include <hip/hip_bf16.h>

#define N_POS 9216
#define NCHUNK 9
#define CHUNKN 1024
#define BATCH 8
#define CDIM 64
#define HEADS 4
#define DHEAD 32
#define INNER 128
#define GROUPS 8
#define EPS 1e-5f

// ws layout: bf16 qkv (q,k in [o][n]; v transposed [n][c]) | stats fp32 | U' bf16 [bk][o][c]
#define QKV_SZ (BATCH*384*N_POS)
#define QKV_BYTES ((size_t)QKV_SZ * 2)
#define ST_SZ  (BATCH*GROUPS*2)

typedef __attribute__((ext_vector_type(8))) short short8;
typedef __attribute__((ext_vector_type(4))) float f32x4;

static __device__ inline unsigned pk2(float a, float b) {
    __hip_bfloat162 h2(__float2bfloat16(a), __float2bfloat16(b));
    return *reinterpret_cast<unsigned*>(&h2);
}
static __device__ inline float bf2f(short s) {
    union { unsigned u; float f; } c; c.u = ((unsigned)(unsigned short)s) << 16; return c.f;
}

__global__ void zero_stats_kernel(float* __restrict__ stats) {
    if (threadIdx.x < ST_SZ) stats[threadIdx.x] = 0.f;
}

// qkv: C[384,9216] = Wqkv[384,64] x x[64,9216] per batch, bf16 MFMA.
// q,k written [o][n]; v (blockIdx.y==2) written transposed [n][c].
__global__ __launch_bounds__(256) void qkv_kernel(const float* __restrict__ x,
        const float* __restrict__ Wqkv, __hip_bfloat16* __restrict__ qkv) {
    int n0 = blockIdx.x * 256;
    int m0 = blockIdx.y * 128;
    int b  = blockIdx.z;
    __shared__ __hip_bfloat16 xs[256][72];   // [n][k]
    __shared__ __hip_bfloat16 wsm[128][72];  // [m][k]
    int t = threadIdx.x;
    int w = t >> 6, l = t & 63;

    {
        const float* xb = x + (size_t)b * CDIM * N_POS + n0 + t;
        #pragma unroll
        for (int c = 0; c < 64; c += 4) {
            float v0 = xb[(size_t)(c + 0) * N_POS];
            float v1 = xb[(size_t)(c + 1) * N_POS];
            float v2 = xb[(size_t)(c + 2) * N_POS];
            float v3 = xb[(size_t)(c + 3) * N_POS];
            uint2 u; u.x = pk2(v0, v1); u.y = pk2(v2, v3);
            *reinterpret_cast<uint2*>(&xs[t][c]) = u;
        }
    }
    {
        int m = t >> 1, ch = (t & 1) * 32;
        const float4* wr = (const float4*)(Wqkv + (size_t)(m0 + m) * CDIM + ch);
        #pragma unroll
        for (int j = 0; j < 8; ++j) {
            float4 v = wr[j];
            uint2 u; u.x = pk2(v.x, v.y); u.y = pk2(v.z, v.w);
            *reinterpret_cast<uint2*>(&wsm[m][ch + j * 4]) = u;
        }
    }
    __syncthreads();

    int lrow = l & 15, lquad = l >> 4;
    f32x4 acc[8][4];
    #pragma unroll
    for (int mt = 0; mt < 8; ++mt)
        #pragma unroll
        for (int nt = 0; nt < 4; ++nt) acc[mt][nt] = (f32x4){0.f, 0.f, 0.f, 0.f};

    #pragma unroll
    for (int ks = 0; ks < 2; ++ks) {
        int k0 = lquad * 8 + ks * 32;
        short8 bfr[4];
        #pragma unroll
        for (int nt = 0; nt < 4; ++nt) {
            int n = w * 64 + nt * 16 + lrow;
            bfr[nt] = *reinterpret_cast<const short8*>(&xs[n][k0]);
        }
        #pragma unroll
        for (int mt = 0; mt < 8; ++mt) {
            short8 afr = *reinterpret_cast<const short8*>(&wsm[mt * 16 + lrow][k0]);
            #pragma unroll
            for (int nt = 0; nt < 4; ++nt)
                acc[mt][nt] = __builtin_amdgcn_mfma_f32_16x16x32_bf16(afr, bfr[nt], acc[mt][nt], 0, 0, 0);
        }
    }

    if (blockIdx.y == 2) {
        // v transposed: vT[n][c], c = m-index in [0,128)
        __hip_bfloat16* vt = qkv + ((size_t)b * 384 + 256) * N_POS;
        #pragma unroll
        for (int mt = 0; mt < 8; ++mt)
            #pragma unroll
            for (int nt = 0; nt < 4; ++nt) {
                int n = n0 + w * 64 + nt * 16 + lrow;
                uint2 u;
                u.x = pk2(acc[mt][nt][0], acc[mt][nt][1]);
                u.y = pk2(acc[mt][nt][2], acc[mt][nt][3]);
                *reinterpret_cast<uint2*>(vt + (size_t)n * 128 + mt * 16 + lquad * 4) = u;
            }
    } else {
        __hip_bfloat16* outp = qkv + ((size_t)b * 384 + m0) * N_POS + n0;
        #pragma unroll
        for (int mt = 0; mt < 8; ++mt)
            #pragma unroll
            for (int nt = 0; nt < 4; ++nt) {
                int n = w * 64 + nt * 16 + lrow;
                #pragma unroll
                for (int r = 0; r < 4; ++r) {
                    int o = mt * 16 + lquad * 4 + r;
                    outp[(size_t)o * N_POS + n] = __float2bfloat16(acc[mt][nt][r]);
                }
            }
    }
}

// per (bh, chunk): S = qs . ks^T (32x32), then U' slice = Wout_h . S  (bf16 [o][c])
__global__ __launch_bounds__(256) void smat_kernel(const __hip_bfloat16* __restrict__ qkv,
        const float* __restrict__ Wout, __hip_bfloat16* __restrict__ Ubf) {
    int bh = blockIdx.x;   // 32
    int ck = blockIdx.y;   // 9
    int b = bh >> 2, h = bh & 3;
    int n0 = ck * CHUNKN;
    __shared__ float qsT[32][129];
    __shared__ float ksT[32][129];
    __shared__ float Mrow[32], iZrow[32];
    __shared__ float Sbuf[4][32][32];
    __shared__ float Sfin[32][32];
    int t = threadIdx.x;
    int w = t >> 6, l = t & 63;
    const __hip_bfloat16* qbase = qkv + ((size_t)b * 384 + h * 32) * N_POS + n0;
    const __hip_bfloat16* kbase = qkv + ((size_t)b * 384 + 128 + h * 32) * N_POS + n0;
    for (int r = 0; r < 8; ++r) {
        int d = w * 8 + r;
        const __hip_bfloat16* qrow = qbase + (size_t)d * N_POS;
        short8 s0 = *reinterpret_cast<const short8*>(qrow + l * 8);
        short8 s1 = *reinterpret_cast<const short8*>(qrow + 512 + l * 8);
        float v[16];
        float mx = -1e30f;
        #pragma unroll
        for (int j = 0; j < 8; ++j) { v[j] = bf2f(s0[j]); v[8 + j] = bf2f(s1[j]); }
        #pragma unroll
        for (int j = 0; j < 16; ++j) mx = fmaxf(mx, v[j]);
        #pragma unroll
        for (int off = 32; off >= 1; off >>= 1) mx = fmaxf(mx, __shfl_xor(mx, off, 64));
        float s = 0.f;
        #pragma unroll
        for (int j = 0; j < 16; ++j) s += __expf(v[j] - mx);
        #pragma unroll
        for (int off = 32; off >= 1; off >>= 1) s += __shfl_xor(s, off, 64);
        if (l == 0) { Mrow[d] = mx; iZrow[d] = 1.f / s; }
    }
    float acc[16];
    #pragma unroll
    for (int i = 0; i < 16; ++i) acc[i] = 0.f;
    int d0 = (l & 7) << 2, e0 = (l >> 3) << 2;
    for (int tile = 0; tile < 8; ++tile) {
        __syncthreads();
        int p = tile * 128 + (t & 127);
        if (t < 128) {
            float kr[32]; float mx = -1e30f;
            #pragma unroll
            for (int d = 0; d < 32; ++d) { kr[d] = __bfloat162float(kbase[(size_t)d * N_POS + p]); mx = fmaxf(mx, kr[d]); }
            float s = 0.f;
            #pragma unroll
            for (int d = 0; d < 32; ++d) { kr[d] = __expf(kr[d] - mx); s += kr[d]; }
            float is = 1.f / s;
            #pragma unroll
            for (int d = 0; d < 32; ++d) ksT[d][t] = kr[d] * is;
        } else {
            int tc = t - 128;
            #pragma unroll
            for (int d = 0; d < 32; ++d) {
                float qv = __bfloat162float(qbase[(size_t)d * N_POS + p]);
                qsT[d][tc] = __expf(qv - Mrow[d]) * iZrow[d];
            }
        }
        __syncthreads();
        #pragma unroll 4
        for (int kk = w * 32; kk < w * 32 + 32; ++kk) {
            float qv[4], kv[4];
            #pragma unroll
            for (int j = 0; j < 4; ++j) { qv[j] = qsT[d0 + j][kk]; kv[j] = ksT[e0 + j][kk]; }
            #pragma unroll
            for (int j = 0; j < 4; ++j)
                #pragma unroll
                for (int jj = 0; jj < 4; ++jj) acc[j * 4 + jj] += qv[j] * kv[jj];
        }
    }
    __syncthreads();
    #pragma unroll
    for (int j = 0; j < 4; ++j)
        #pragma unroll
        for (int jj = 0; jj < 4; ++jj) Sbuf[w][d0 + j][e0 + jj] = acc[j * 4 + jj];
    __syncthreads();
    {
        // Sfin[d][dd] = sum over 4 wave partials; thread t writes float4 at [t>>3][(t&7)*4]
        int d = t >> 3, ddb = (t & 7) * 4;
        float4 fs;
        fs.x = Sbuf[0][d][ddb+0] + Sbuf[1][d][ddb+0] + Sbuf[2][d][ddb+0] + Sbuf[3][d][ddb+0];
        fs.y = Sbuf[0][d][ddb+1] + Sbuf[1][d][ddb+1] + Sbuf[2][d][ddb+1] + Sbuf[3][d][ddb+1];
        fs.z = Sbuf[0][d][ddb+2] + Sbuf[1][d][ddb+2] + Sbuf[2][d][ddb+2] + Sbuf[3][d][ddb+2];
        fs.w = Sbuf[0][d][ddb+3] + Sbuf[1][d][ddb+3] + Sbuf[2][d][ddb+3] + Sbuf[3][d][ddb+3];
        *reinterpret_cast<float4*>(&Sfin[d][ddb]) = fs;
    }
    __syncthreads();
    // U'[o][h*32+dd] = sum_d Wout[o][h*32+d] * Sfin[d][dd]; thread: o = t&63, dd in [8*(t>>6), +8)
    {
        int o = t & 63, wv = t >> 6;
        float wreg[32];
        const float4* wr = (const float4*)(Wout + (size_t)o * 128 + h * 32);
        #pragma unroll
        for (int j = 0; j < 8; ++j) {
            float4 f = wr[j];
            wreg[j*4+0] = f.x; wreg[j*4+1] = f.y; wreg[j*4+2] = f.z; wreg[j*4+3] = f.w;
        }
        float ua[8];
        #pragma unroll
        for (int j = 0; j < 8; ++j) ua[j] = 0.f;
        for (int d = 0; d < 32; ++d) {
            float4 sA = *reinterpret_cast<const float4*>(&Sfin[d][wv * 8]);
            float4 sB = *reinterpret_cast<const float4*>(&Sfin[d][wv * 8 + 4]);
            float wd = wreg[d];
            ua[0] += wd * sA.x; ua[1] += wd * sA.y; ua[2] += wd * sA.z; ua[3] += wd * sA.w;
            ua[4] += wd * sB.x; ua[5] += wd * sB.y; ua[6] += wd * sB.z; ua[7] += wd * sB.w;
        }
        uint4 up;
        up.x = pk2(ua[0], ua[1]); up.y = pk2(ua[2], ua[3]);
        up.z = pk2(ua[4], ua[5]); up.w = pk2(ua[6], ua[7]);
        __hip_bfloat16* Up = Ubf + ((size_t)(b * NCHUNK + ck) * 64 + o) * 128 + h * 32 + wv * 8;
        *reinterpret_cast<uint4*>(Up) = up;
    }
}

// y = U'(64x128) . vT^T(128 x n) via MFMA, direct-global fragments; fused bias + GN stats.
__global__ __launch_bounds__(256) void y_kernel(const __hip_bfloat16* __restrict__ qkv,
        const __hip_bfloat16* __restrict__ Ubf, const float* __restrict__ bout,
        float* __restrict__ y, float* __restrict__ stats) {
    int bx = blockIdx.x;   // 72 tiles of 128 positions
    int b  = blockIdx.y;   // 8
    int ck = bx >> 3;
    __shared__ float gsum[8], gsq[8];
    int t = threadIdx.x, w = t >> 6, l = t & 63;
    int l15 = l & 15, quad = l >> 4;
    if (t < 8) { gsum[t] = 0.f; gsq[t] = 0.f; }
    __syncthreads();
    const __hip_bfloat16* vt = qkv + ((size_t)b * 384 + 256) * N_POS;
    const __hip_bfloat16* Ub = Ubf + (size_t)(b * NCHUNK + ck) * 64 * 128;
    int nbase = bx * 128 + w * 32;
    f32x4 acc[4][2];
    #pragma unroll
    for (int mt = 0; mt < 4; ++mt) { acc[mt][0] = (f32x4){0,0,0,0}; acc[mt][1] = (f32x4){0,0,0,0}; }
    #pragma unroll
    for (int ks = 0; ks < 4; ++ks) {
        int k0 = ks * 32 + quad * 8;
        short8 bf[2];
        #pragma unroll
        for (int nt = 0; nt < 2; ++nt)
            bf[nt] = *reinterpret_cast<const short8*>(vt + (size_t)(nbase + nt * 16 + l15) * 128 + k0);
        #pragma unroll
        for (int mt = 0; mt < 4; ++mt) {
            short8 af = *reinterpret_cast<const short8*>(Ub + (size_t)(mt * 16 + l15) * 128 + k0);
            acc[mt][0] = __builtin_amdgcn_mfma_f32_16x16x32_bf16(af, bf[0], acc[mt][0], 0, 0, 0);
            acc[mt][1] = __builtin_amdgcn_mfma_f32_16x16x32_bf16(af, bf[1], acc[mt][1], 0, 0, 0);
        }
    }
    float gsl[4], gql[4];
    #pragma unroll
    for (int mt = 0; mt < 4; ++mt) { gsl[mt] = 0.f; gql[mt] = 0.f; }
    float* yb = y + (size_t)b * CDIM * N_POS;
    #pragma unroll
    for (int mt = 0; mt < 4; ++mt) {
        float4 bo = *reinterpret_cast<const float4*>(bout + mt * 16 + quad * 4);
        const float* bop = reinterpret_cast<const float*>(&bo);
        #pragma unroll
        for (int nt = 0; nt < 2; ++nt) {
            int n = nbase + nt * 16 + l15;
            #pragma unroll
            for (int r = 0; r < 4; ++r) {
                int o = mt * 16 + quad * 4 + r;
                float val = acc[mt][nt][r] + bop[r];
                yb[(size_t)o * N_POS + n] = val;
                gsl[mt] += val; gql[mt] += val * val;
            }
        }
    }
    // reduce within 32-lane halves (quads 0,1 -> even groups; 2,3 -> odd)
    #pragma unroll
    for (int off = 16; off >= 1; off >>= 1) {
        #pragma unroll
        for (int mt = 0; mt < 4; ++mt) {
            gsl[mt] += __shfl_xor(gsl[mt], off, 64);
            gql[mt] += __shfl_xor(gql[mt], off, 64);
        }
    }
    if (l == 0 || l == 32) {
        int qh = quad >> 1;
        #pragma unroll
        for (int mt = 0; mt < 4; ++mt) {
            atomicAdd(&gsum[2 * mt + qh], gsl[mt]);
            atomicAdd(&gsq[2 * mt + qh], gql[mt]);
        }
    }
    __syncthreads();
    if (t < 8) {
        atomicAdd(&stats[(b * 8 + t) * 2],     gsum[t]);
        atomicAdd(&stats[(b * 8 + t) * 2 + 1], gsq[t]);
    }
}

__global__ __launch_bounds__(256) void gn_kernel(float* __restrict__ y,
        const float* __restrict__ stats, const float* __restrict__ gamma,
        const float* __restrict__ beta) {
    int i4 = blockIdx.x * 256 + threadIdx.x;
    if (i4 >= (BATCH * CDIM * N_POS) / 4) return;
    int base = i4 * 4;
    int bc = base / N_POS;
    int c = bc & 63, b = bc >> 6;
    int g = c >> 3;
    float s = stats[(b * 8 + g) * 2], q = stats[(b * 8 + g) * 2 + 1];
    const float invN = 1.f / (8.f * N_POS);
    float mean = s * invN;
    float var = q * invN - mean * mean;
    float sc = rsqrtf(var + EPS);
    float ga = gamma[c] * sc;
    float be = beta[c] - mean * sc * gamma[c];
    float4 v = ((float4*)y)[i4];
    v.x = v.x * ga + be; v.y = v.y * ga + be; v.z = v.z * ga + be; v.w = v.w * ga + be;
    ((float4*)y)[i4] = v;
}

extern "C" void kernel_launch(void* const* d_in, const int* in_sizes, int n_in,
                              void* d_out, int out_size, void* d_ws, size_t ws_size,
                              hipStream_t stream) {
    const float* x     = (const float*)d_in[0];
    const float* Wqkv  = (const float*)d_in[1];
    const float* Wout  = (const float*)d_in[2];
    const float* bout  = (const float*)d_in[3];
    const float* gamma = (const float*)d_in[4];
    const float* beta  = (const float*)d_in[5];
    float* out = (float*)d_out;

    __hip_bfloat16* qkv = (__hip_bfloat16*)d_ws;
    float* stats = (float*)((char*)d_ws + QKV_BYTES);
    __hip_bfloat16* Ubf = (__hip_bfloat16*)((char*)d_ws + QKV_BYTES + 1024);

    zero_stats_kernel<<<1, 128, 0, stream>>>(stats);
    qkv_kernel<<<dim3(36, 3, BATCH), 256, 0, stream>>>(x, Wqkv, qkv);
    smat_kernel<<<dim3(32, NCHUNK), 256, 0, stream>>>(qkv, Wout, Ubf);
    y_kernel<<<dim3(72, BATCH), 256, 0, stream>>>(qkv, Ubf, bout, out, stats);
    gn_kernel<<<dim3((BATCH * CDIM * N_POS / 4 + 255) / 256), 256, 0, stream>>>(out, stats, gamma, beta);
}

// Round 5
// 140.590 us; speedup vs baseline: 3.0559x; 1.1865x over previous
//
#include <hip/hip_runtime.h>
#include <hip/hip_bf16.h>

#define N_POS 9216
#define NCHUNK 9
#define CHUNKN 1024
#define BATCH 8
#define CDIM 64
#define HEADS 4
#define DHEAD 32
#define INNER 128
#define GROUPS 8
#define EPS 1e-5f

// ws layout: bf16 qkv (q,k [o][n]; v transposed [n][c]) | fp32 stats(128) | fp32 P(294912) | bf16 U'
#define QKV_SZ (BATCH*384*N_POS)
#define QKV_BYTES ((size_t)QKV_SZ * 2)
#define P_SZ (BATCH*HEADS*NCHUNK*1024)   // 294912
#define ZTOT (128 + P_SZ)                // floats to zero

typedef __attribute__((ext_vector_type(8))) short short8;
typedef __attribute__((ext_vector_type(4))) float f32x4;

static __device__ inline unsigned pk2(float a, float b) {
    __hip_bfloat162 h2(__float2bfloat16(a), __float2bfloat16(b));
    return *reinterpret_cast<unsigned*>(&h2);
}
static __device__ inline float bf2f(short s) {
    union { unsigned u; float f; } c; c.u = ((unsigned)(unsigned short)s) << 16; return c.f;
}

__global__ __launch_bounds__(256) void zero_kernel(float* __restrict__ p) {
    int i = blockIdx.x * 256 + threadIdx.x;
    if (i < ZTOT) p[i] = 0.f;
}

// qkv: C[384,9216] = Wqkv[384,64] x x[64,9216] per batch, bf16 MFMA.
// q,k written [o][n]; v (blockIdx.y==2) written transposed [n][c].
__global__ __launch_bounds__(256) void qkv_kernel(const float* __restrict__ x,
        const float* __restrict__ Wqkv, __hip_bfloat16* __restrict__ qkv) {
    int n0 = blockIdx.x * 256;
    int m0 = blockIdx.y * 128;
    int b  = blockIdx.z;
    __shared__ __hip_bfloat16 xs[256][72];   // [n][k]
    __shared__ __hip_bfloat16 wsm[128][72];  // [m][k]
    int t = threadIdx.x;
    int w = t >> 6, l = t & 63;

    {
        const float* xb = x + (size_t)b * CDIM * N_POS + n0 + t;
        #pragma unroll
        for (int c = 0; c < 64; c += 4) {
            float v0 = xb[(size_t)(c + 0) * N_POS];
            float v1 = xb[(size_t)(c + 1) * N_POS];
            float v2 = xb[(size_t)(c + 2) * N_POS];
            float v3 = xb[(size_t)(c + 3) * N_POS];
            uint2 u; u.x = pk2(v0, v1); u.y = pk2(v2, v3);
            *reinterpret_cast<uint2*>(&xs[t][c]) = u;
        }
    }
    {
        int m = t >> 1, ch = (t & 1) * 32;
        const float4* wr = (const float4*)(Wqkv + (size_t)(m0 + m) * CDIM + ch);
        #pragma unroll
        for (int j = 0; j < 8; ++j) {
            float4 v = wr[j];
            uint2 u; u.x = pk2(v.x, v.y); u.y = pk2(v.z, v.w);
            *reinterpret_cast<uint2*>(&wsm[m][ch + j * 4]) = u;
        }
    }
    __syncthreads();

    int lrow = l & 15, lquad = l >> 4;
    f32x4 acc[8][4];
    #pragma unroll
    for (int mt = 0; mt < 8; ++mt)
        #pragma unroll
        for (int nt = 0; nt < 4; ++nt) acc[mt][nt] = (f32x4){0.f, 0.f, 0.f, 0.f};

    #pragma unroll
    for (int ks = 0; ks < 2; ++ks) {
        int k0 = lquad * 8 + ks * 32;
        short8 bfr[4];
        #pragma unroll
        for (int nt = 0; nt < 4; ++nt) {
            int n = w * 64 + nt * 16 + lrow;
            bfr[nt] = *reinterpret_cast<const short8*>(&xs[n][k0]);
        }
        #pragma unroll
        for (int mt = 0; mt < 8; ++mt) {
            short8 afr = *reinterpret_cast<const short8*>(&wsm[mt * 16 + lrow][k0]);
            #pragma unroll
            for (int nt = 0; nt < 4; ++nt)
                acc[mt][nt] = __builtin_amdgcn_mfma_f32_16x16x32_bf16(afr, bfr[nt], acc[mt][nt], 0, 0, 0);
        }
    }

    if (blockIdx.y == 2) {
        __hip_bfloat16* vt = qkv + ((size_t)b * 384 + 256) * N_POS;
        #pragma unroll
        for (int mt = 0; mt < 8; ++mt)
            #pragma unroll
            for (int nt = 0; nt < 4; ++nt) {
                int n = n0 + w * 64 + nt * 16 + lrow;
                uint2 u;
                u.x = pk2(acc[mt][nt][0], acc[mt][nt][1]);
                u.y = pk2(acc[mt][nt][2], acc[mt][nt][3]);
                *reinterpret_cast<uint2*>(vt + (size_t)n * 128 + mt * 16 + lquad * 4) = u;
            }
    } else {
        __hip_bfloat16* outp = qkv + ((size_t)b * 384 + m0) * N_POS + n0;
        #pragma unroll
        for (int mt = 0; mt < 8; ++mt)
            #pragma unroll
            for (int nt = 0; nt < 4; ++nt) {
                int n = w * 64 + nt * 16 + lrow;
                #pragma unroll
                for (int r = 0; r < 4; ++r) {
                    int o = mt * 16 + lquad * 4 + r;
                    outp[(size_t)o * N_POS + n] = __float2bfloat16(acc[mt][nt][r]);
                }
            }
    }
}

// P[d][dd] += sum_{i in tile} exp(q[d,i]) * ks[dd,i]   (S = P / rowsum(P) later)
// grid (32 bh, 9 ck, 4 ptile), 256 thr = 4 waves; each wave one 16x16 quarter of P.
__global__ __launch_bounds__(256) void smat_part(const __hip_bfloat16* __restrict__ qkv,
        float* __restrict__ Pg) {
    int bh = blockIdx.x;   // 32
    int ck = blockIdx.y;   // 9
    int pt = blockIdx.z;   // 4
    int b = bh >> 2, h = bh & 3;
    int p0 = ck * CHUNKN + pt * 256;
    __shared__ __hip_bfloat16 qsb[32][264];  // 264*2B=528B=132 dw; 132%32=4 -> 2-way (free)
    __shared__ __hip_bfloat16 ksb[32][264];
    int t = threadIdx.x, w = t >> 6, l = t & 63;
    const __hip_bfloat16* qbase = qkv + ((size_t)b * 384 + h * 32) * N_POS + p0 + t;
    const __hip_bfloat16* kbase = qkv + ((size_t)b * 384 + 128 + h * 32) * N_POS + p0 + t;
    // k: softmax over 32 channels at position t (register column)
    {
        float kr[32]; float mx = -1e30f;
        #pragma unroll
        for (int d = 0; d < 32; ++d) { kr[d] = bf2f(*(const short*)(kbase + (size_t)d * N_POS)); mx = fmaxf(mx, kr[d]); }
        float s = 0.f;
        #pragma unroll
        for (int d = 0; d < 32; ++d) { kr[d] = __expf(kr[d] - mx); s += kr[d]; }
        float is = 1.f / s;
        #pragma unroll
        for (int d = 0; d < 32; ++d) ksb[d][t] = __float2bfloat16(kr[d] * is);
    }
    // q: raw exp (no max shift; q ~ N(0,1) so exp is safe; normalization deferred)
    #pragma unroll
    for (int d = 0; d < 32; ++d)
        qsb[d][t] = __float2bfloat16(__expf(bf2f(*(const short*)(qbase + (size_t)d * N_POS))));
    __syncthreads();

    int mt = w >> 1, nt = w & 1;
    int l15 = l & 15, quad = l >> 4;
    f32x4 acc = (f32x4){0.f, 0.f, 0.f, 0.f};
    #pragma unroll
    for (int step = 0; step < 8; ++step) {
        int k0 = step * 32 + quad * 8;
        short8 af = *reinterpret_cast<const short8*>(&qsb[mt * 16 + l15][k0]);
        short8 bf = *reinterpret_cast<const short8*>(&ksb[nt * 16 + l15][k0]);
        acc = __builtin_amdgcn_mfma_f32_16x16x32_bf16(af, bf, acc, 0, 0, 0);
    }
    float* Pp = Pg + ((size_t)bh * NCHUNK + ck) * 1024;
    #pragma unroll
    for (int r = 0; r < 4; ++r)
        atomicAdd(&Pp[(mt * 16 + quad * 4 + r) * 32 + nt * 16 + l15], acc[r]);
}

// U'[o][h*32+dd] = sum_d Wout[o][h*32+d] * (1/Z_d) * P[d][dd];  Z_d = rowsum(P)
// grid (9 ck, 8 b, 4 h), 256 thr.
__global__ __launch_bounds__(256) void umat_kernel(const float* __restrict__ Wout,
        const float* __restrict__ Pg, __hip_bfloat16* __restrict__ Ubf) {
    int ck = blockIdx.x, b = blockIdx.y, h = blockIdx.z;
    int bh = b * 4 + h;
    __shared__ float Pl[32][32];
    __shared__ float iZ[32];
    int t = threadIdx.x;
    const float* Pp = Pg + ((size_t)bh * NCHUNK + ck) * 1024;
    ((float4*)Pl)[t] = ((const float4*)Pp)[t];
    __syncthreads();
    if (t < 32) {
        float s = 0.f;
        #pragma unroll
        for (int c = 0; c < 32; ++c) s += Pl[t][c];
        iZ[t] = 1.f / s;
    }
    __syncthreads();
    int o = t & 63, wv = t >> 6;
    float wz[32];
    {
        const float4* wr = (const float4*)(Wout + (size_t)o * 128 + h * 32);
        #pragma unroll
        for (int j = 0; j < 8; ++j) {
            float4 f = wr[j];
            wz[j*4+0] = f.x * iZ[j*4+0]; wz[j*4+1] = f.y * iZ[j*4+1];
            wz[j*4+2] = f.z * iZ[j*4+2]; wz[j*4+3] = f.w * iZ[j*4+3];
        }
    }
    float ua[8];
    #pragma unroll
    for (int j = 0; j < 8; ++j) ua[j] = 0.f;
    for (int d = 0; d < 32; ++d) {
        float wd = wz[d];
        #pragma unroll
        for (int j = 0; j < 8; ++j) ua[j] += wd * Pl[d][wv * 8 + j];
    }
    uint4 up;
    up.x = pk2(ua[0], ua[1]); up.y = pk2(ua[2], ua[3]);
    up.z = pk2(ua[4], ua[5]); up.w = pk2(ua[6], ua[7]);
    __hip_bfloat16* Up = Ubf + ((size_t)(b * NCHUNK + ck) * 64 + o) * 128 + h * 32 + wv * 8;
    *reinterpret_cast<uint4*>(Up) = up;
}

// y = U'(64x128) . vT^T(128 x n) via MFMA, direct-global fragments; fused bias + GN stats.
__global__ __launch_bounds__(256) void y_kernel(const __hip_bfloat16* __restrict__ qkv,
        const __hip_bfloat16* __restrict__ Ubf, const float* __restrict__ bout,
        float* __restrict__ y, float* __restrict__ stats) {
    int bx = blockIdx.x;   // 72 tiles of 128 positions
    int b  = blockIdx.y;   // 8
    int ck = bx >> 3;
    __shared__ float gsum[8], gsq[8];
    int t = threadIdx.x, w = t >> 6, l = t & 63;
    int l15 = l & 15, quad = l >> 4;
    if (t < 8) { gsum[t] = 0.f; gsq[t] = 0.f; }
    __syncthreads();
    const __hip_bfloat16* vt = qkv + ((size_t)b * 384 + 256) * N_POS;
    const __hip_bfloat16* Ub = Ubf + (size_t)(b * NCHUNK + ck) * 64 * 128;
    int nbase = bx * 128 + w * 32;
    f32x4 acc[4][2];
    #pragma unroll
    for (int mt = 0; mt < 4; ++mt) { acc[mt][0] = (f32x4){0,0,0,0}; acc[mt][1] = (f32x4){0,0,0,0}; }
    #pragma unroll
    for (int ks = 0; ks < 4; ++ks) {
        int k0 = ks * 32 + quad * 8;
        short8 bf[2];
        #pragma unroll
        for (int nt = 0; nt < 2; ++nt)
            bf[nt] = *reinterpret_cast<const short8*>(vt + (size_t)(nbase + nt * 16 + l15) * 128 + k0);
        #pragma unroll
        for (int mt = 0; mt < 4; ++mt) {
            short8 af = *reinterpret_cast<const short8*>(Ub + (size_t)(mt * 16 + l15) * 128 + k0);
            acc[mt][0] = __builtin_amdgcn_mfma_f32_16x16x32_bf16(af, bf[0], acc[mt][0], 0, 0, 0);
            acc[mt][1] = __builtin_amdgcn_mfma_f32_16x16x32_bf16(af, bf[1], acc[mt][1], 0, 0, 0);
        }
    }
    float gsl[4], gql[4];
    #pragma unroll
    for (int mt = 0; mt < 4; ++mt) { gsl[mt] = 0.f; gql[mt] = 0.f; }
    float* yb = y + (size_t)b * CDIM * N_POS;
    #pragma unroll
    for (int mt = 0; mt < 4; ++mt) {
        float4 bo = *reinterpret_cast<const float4*>(bout + mt * 16 + quad * 4);
        const float* bop = reinterpret_cast<const float*>(&bo);
        #pragma unroll
        for (int nt = 0; nt < 2; ++nt) {
            int n = nbase + nt * 16 + l15;
            #pragma unroll
            for (int r = 0; r < 4; ++r) {
                int o = mt * 16 + quad * 4 + r;
                float val = acc[mt][nt][r] + bop[r];
                yb[(size_t)o * N_POS + n] = val;
                gsl[mt] += val; gql[mt] += val * val;
            }
        }
    }
    #pragma unroll
    for (int off = 16; off >= 1; off >>= 1) {
        #pragma unroll
        for (int mt = 0; mt < 4; ++mt) {
            gsl[mt] += __shfl_xor(gsl[mt], off, 64);
            gql[mt] += __shfl_xor(gql[mt], off, 64);
        }
    }
    if (l == 0 || l == 32) {
        int qh = quad >> 1;
        #pragma unroll
        for (int mt = 0; mt < 4; ++mt) {
            atomicAdd(&gsum[2 * mt + qh], gsl[mt]);
            atomicAdd(&gsq[2 * mt + qh], gql[mt]);
        }
    }
    __syncthreads();
    if (t < 8) {
        atomicAdd(&stats[(b * 8 + t) * 2],     gsum[t]);
        atomicAdd(&stats[(b * 8 + t) * 2 + 1], gsq[t]);
    }
}

__global__ __launch_bounds__(256) void gn_kernel(float* __restrict__ y,
        const float* __restrict__ stats, const float* __restrict__ gamma,
        const float* __restrict__ beta) {
    int i4 = blockIdx.x * 256 + threadIdx.x;
    if (i4 >= (BATCH * CDIM * N_POS) / 4) return;
    int base = i4 * 4;
    int bc = base / N_POS;
    int c = bc & 63, b = bc >> 6;
    int g = c >> 3;
    float s = stats[(b * 8 + g) * 2], q = stats[(b * 8 + g) * 2 + 1];
    const float invN = 1.f / (8.f * N_POS);
    float mean = s * invN;
    float var = q * invN - mean * mean;
    float sc = rsqrtf(var + EPS);
    float ga = gamma[c] * sc;
    float be = beta[c] - mean * sc * gamma[c];
    float4 v = ((float4*)y)[i4];
    v.x = v.x * ga + be; v.y = v.y * ga + be; v.z = v.z * ga + be; v.w = v.w * ga + be;
    ((float4*)y)[i4] = v;
}

extern "C" void kernel_launch(void* const* d_in, const int* in_sizes, int n_in,
                              void* d_out, int out_size, void* d_ws, size_t ws_size,
                              hipStream_t stream) {
    const float* x     = (const float*)d_in[0];
    const float* Wqkv  = (const float*)d_in[1];
    const float* Wout  = (const float*)d_in[2];
    const float* bout  = (const float*)d_in[3];
    const float* gamma = (const float*)d_in[4];
    const float* beta  = (const float*)d_in[5];
    float* out = (float*)d_out;

    __hip_bfloat16* qkv = (__hip_bfloat16*)d_ws;
    float* stats = (float*)((char*)d_ws + QKV_BYTES);
    float* Pg    = stats + 128;
    __hip_bfloat16* Ubf = (__hip_bfloat16*)(Pg + P_SZ);

    zero_kernel<<<dim3((ZTOT + 255) / 256), 256, 0, stream>>>(stats);
    qkv_kernel<<<dim3(36, 3, BATCH), 256, 0, stream>>>(x, Wqkv, qkv);
    smat_part<<<dim3(32, NCHUNK, 4), 256, 0, stream>>>(qkv, Pg);
    umat_kernel<<<dim3(NCHUNK, BATCH, HEADS), 256, 0, stream>>>(Wout, Pg, Ubf);
    y_kernel<<<dim3(72, BATCH), 256, 0, stream>>>(qkv, Ubf, bout, out, stats);
    gn_kernel<<<dim3((BATCH * CDIM * N_POS / 4 + 255) / 256), 256, 0, stream>>>(out, stats, gamma, beta);
}

// Round 6
// 133.226 us; speedup vs baseline: 3.2248x; 1.0553x over previous
//
#include <hip/hip_runtime.h>
#include <hip/hip_bf16.h>

#define N_POS 9216
#define NCHUNK 9
#define CHUNKN 1024
#define BATCH 8
#define CDIM 64
#define HEADS 4
#define GROUPS 8
#define EPS 1e-5f

// q,k,v each stored position-major: sec[b][n][128] bf16
#define SEC_SZ ((size_t)BATCH * N_POS * 128)
#define QKV_BYTES (3 * SEC_SZ * 2)
#define PPART_SZ ((size_t)32 * NCHUNK * 1024)   // floats per pt-partial

typedef __attribute__((ext_vector_type(8))) short short8;
typedef __attribute__((ext_vector_type(4))) float f32x4;

static __device__ inline unsigned pk2(float a, float b) {
    __hip_bfloat162 h2(__float2bfloat16(a), __float2bfloat16(b));
    return *reinterpret_cast<unsigned*>(&h2);
}
static __device__ inline float bf2f(short s) {
    union { unsigned u; float f; } c; c.u = ((unsigned)(unsigned short)s) << 16; return c.f;
}

// qkv: per batch C[384,9216] = Wqkv[384,64] x x[64,9216], bf16 MFMA.
// Output written position-major [n][128] per section via LDS transpose.
__global__ __launch_bounds__(256) void qkv_kernel(const float* __restrict__ x,
        const float* __restrict__ Wqkv, __hip_bfloat16* __restrict__ qkv) {
    int n0  = blockIdx.x * 256;
    int sec = blockIdx.y;           // 0=q 1=k 2=v
    int b   = blockIdx.z;
    __shared__ __align__(16) char lds_raw[256 * 136 * 2];   // 69632 B
    __hip_bfloat16 (*xs)[72]    = (__hip_bfloat16(*)[72])lds_raw;              // [256][72]
    __hip_bfloat16 (*wsm)[72]   = (__hip_bfloat16(*)[72])(lds_raw + 256*72*2); // [128][72]
    __hip_bfloat16 (*vbuf)[136] = (__hip_bfloat16(*)[136])lds_raw;             // [256][136]
    int t = threadIdx.x;
    int w = t >> 6, l = t & 63;

    {
        const float* xb = x + (size_t)b * CDIM * N_POS + n0 + t;
        #pragma unroll
        for (int c = 0; c < 64; c += 4) {
            float v0 = xb[(size_t)(c + 0) * N_POS];
            float v1 = xb[(size_t)(c + 1) * N_POS];
            float v2 = xb[(size_t)(c + 2) * N_POS];
            float v3 = xb[(size_t)(c + 3) * N_POS];
            uint2 u; u.x = pk2(v0, v1); u.y = pk2(v2, v3);
            *reinterpret_cast<uint2*>(&xs[t][c]) = u;
        }
    }
    {
        int m = t >> 1, ch = (t & 1) * 32;
        const float4* wr = (const float4*)(Wqkv + ((size_t)sec * 128 + m) * CDIM + ch);
        #pragma unroll
        for (int j = 0; j < 8; ++j) {
            float4 v = wr[j];
            uint2 u; u.x = pk2(v.x, v.y); u.y = pk2(v.z, v.w);
            *reinterpret_cast<uint2*>(&wsm[m][ch + j * 4]) = u;
        }
    }
    __syncthreads();

    int lrow = l & 15, lquad = l >> 4;
    f32x4 acc[8][4];
    #pragma unroll
    for (int mt = 0; mt < 8; ++mt)
        #pragma unroll
        for (int nt = 0; nt < 4; ++nt) acc[mt][nt] = (f32x4){0.f, 0.f, 0.f, 0.f};

    #pragma unroll
    for (int ks = 0; ks < 2; ++ks) {
        int k0 = lquad * 8 + ks * 32;
        short8 bfr[4];
        #pragma unroll
        for (int nt = 0; nt < 4; ++nt) {
            int n = w * 64 + nt * 16 + lrow;
            bfr[nt] = *reinterpret_cast<const short8*>(&xs[n][k0]);
        }
        #pragma unroll
        for (int mt = 0; mt < 8; ++mt) {
            short8 afr = *reinterpret_cast<const short8*>(&wsm[mt * 16 + lrow][k0]);
            #pragma unroll
            for (int nt = 0; nt < 4; ++nt)
                acc[mt][nt] = __builtin_amdgcn_mfma_f32_16x16x32_bf16(afr, bfr[nt], acc[mt][nt], 0, 0, 0);
        }
    }
    __syncthreads();   // done reading xs/wsm; reuse LDS as vbuf

    // transpose to [n][c] in LDS (stride 136: write banks 2-way = free)
    #pragma unroll
    for (int mt = 0; mt < 8; ++mt)
        #pragma unroll
        for (int nt = 0; nt < 4; ++nt) {
            int n = w * 64 + nt * 16 + lrow;
            uint2 u;
            u.x = pk2(acc[mt][nt][0], acc[mt][nt][1]);
            u.y = pk2(acc[mt][nt][2], acc[mt][nt][3]);
            *reinterpret_cast<uint2*>(&vbuf[n][mt * 16 + lquad * 4]) = u;
        }
    __syncthreads();

    // coalesced store: 16 iters x 16B/lane
    __hip_bfloat16* outb = qkv + (size_t)sec * SEC_SZ + ((size_t)b * N_POS + n0) * 128;
    int rg = t >> 4, c0 = (t & 15) * 8;
    #pragma unroll
    for (int j = 0; j < 16; ++j) {
        int r = j * 16 + rg;
        *reinterpret_cast<uint4*>(outb + (size_t)r * 128 + c0) =
            *reinterpret_cast<const uint4*>(&vbuf[r][c0]);
    }
}

// P_part[pt][bh][ck][32][32] = sum_{i in 256-tile} exp(q[d,i]) * ks[dd,i]
// grid (32 bh, 9 ck, 4 pt); 4 waves, each one 16x16 quarter of P.
__global__ __launch_bounds__(256) void smat_part(const __hip_bfloat16* __restrict__ qkv,
        float* __restrict__ Pparts) {
    int bh = blockIdx.x, ck = blockIdx.y, pt = blockIdx.z;
    int b = bh >> 2, h = bh & 3;
    int p = ck * CHUNKN + pt * 256 + threadIdx.x;
    __shared__ __hip_bfloat16 qsb[32][264];
    __shared__ __hip_bfloat16 ksb[32][264];
    int t = threadIdx.x, w = t >> 6, l = t & 63;
    const __hip_bfloat16* qp = qkv + ((size_t)b * N_POS + p) * 128 + h * 32;
    const __hip_bfloat16* kp = qkv + SEC_SZ + ((size_t)b * N_POS + p) * 128 + h * 32;
    // k: channel softmax at this position (contiguous 64B load)
    {
        short8 kv4[4];
        #pragma unroll
        for (int j = 0; j < 4; ++j) kv4[j] = *reinterpret_cast<const short8*>(kp + j * 8);
        float kr[32]; float mx = -1e30f;
        #pragma unroll
        for (int j = 0; j < 4; ++j)
            #pragma unroll
            for (int e = 0; e < 8; ++e) { kr[j*8+e] = bf2f(kv4[j][e]); mx = fmaxf(mx, kr[j*8+e]); }
        float s = 0.f;
        #pragma unroll
        for (int d = 0; d < 32; ++d) { kr[d] = __expf(kr[d] - mx); s += kr[d]; }
        float is = 1.f / s;
        #pragma unroll
        for (int d = 0; d < 32; ++d) ksb[d][t] = __float2bfloat16(kr[d] * is);
    }
    // q: raw exp (normalization deferred to umat via rowsum identity)
    {
        short8 qv4[4];
        #pragma unroll
        for (int j = 0; j < 4; ++j) qv4[j] = *reinterpret_cast<const short8*>(qp + j * 8);
        #pragma unroll
        for (int j = 0; j < 4; ++j)
            #pragma unroll
            for (int e = 0; e < 8; ++e)
                qsb[j*8+e][t] = __float2bfloat16(__expf(bf2f(qv4[j][e])));
    }
    __syncthreads();

    int mt = w >> 1, nt = w & 1;
    int l15 = l & 15, quad = l >> 4;
    f32x4 acc = (f32x4){0.f, 0.f, 0.f, 0.f};
    #pragma unroll
    for (int step = 0; step < 8; ++step) {
        int k0 = step * 32 + quad * 8;
        short8 af = *reinterpret_cast<const short8*>(&qsb[mt * 16 + l15][k0]);
        short8 bf = *reinterpret_cast<const short8*>(&ksb[nt * 16 + l15][k0]);
        acc = __builtin_amdgcn_mfma_f32_16x16x32_bf16(af, bf, acc, 0, 0, 0);
    }
    float* Pp = Pparts + (size_t)pt * PPART_SZ + ((size_t)bh * NCHUNK + ck) * 1024;
    #pragma unroll
    for (int r = 0; r < 4; ++r)
        Pp[(mt * 16 + quad * 4 + r) * 32 + nt * 16 + l15] = acc[r];
}

// U'[o][h*32+dd] = sum_d Wout[o][h*32+d] * (1/Z_d) * P[d][dd];  Z_d = rowsum(P)
// Also zeroes GN stats (blocks ck==0,h==0) before y_kernel runs.
__global__ __launch_bounds__(256) void umat_kernel(const float* __restrict__ Wout,
        const float* __restrict__ Pparts, __hip_bfloat16* __restrict__ Ubf,
        float* __restrict__ stats) {
    int ck = blockIdx.x, b = blockIdx.y, h = blockIdx.z;
    int bh = b * 4 + h;
    int t = threadIdx.x;
    if (ck == 0 && h == 0 && t < 16) stats[b * 16 + t] = 0.f;
    __shared__ float Pl[32][32];
    __shared__ float iZ[32];
    size_t base4 = (((size_t)bh * NCHUNK + ck) * 1024) / 4;
    {
        const float4* P0 = (const float4*)Pparts + base4;
        const float4* P1 = (const float4*)(Pparts + PPART_SZ) + base4;
        const float4* P2 = (const float4*)(Pparts + 2 * PPART_SZ) + base4;
        const float4* P3 = (const float4*)(Pparts + 3 * PPART_SZ) + base4;
        float4 a = P0[t], bb = P1[t], c = P2[t], d = P3[t];
        float4 s; s.x = a.x+bb.x+c.x+d.x; s.y = a.y+bb.y+c.y+d.y;
        s.z = a.z+bb.z+c.z+d.z; s.w = a.w+bb.w+c.w+d.w;
        ((float4*)Pl)[t] = s;
    }
    __syncthreads();
    if (t < 32) {
        float s = 0.f;
        #pragma unroll
        for (int c = 0; c < 32; ++c) s += Pl[t][c];
        iZ[t] = 1.f / s;
    }
    __syncthreads();
    int o = t & 63, wv = t >> 6;
    float wz[32];
    {
        const float4* wr = (const float4*)(Wout + (size_t)o * 128 + h * 32);
        #pragma unroll
        for (int j = 0; j < 8; ++j) {
            float4 f = wr[j];
            wz[j*4+0] = f.x * iZ[j*4+0]; wz[j*4+1] = f.y * iZ[j*4+1];
            wz[j*4+2] = f.z * iZ[j*4+2]; wz[j*4+3] = f.w * iZ[j*4+3];
        }
    }
    float ua[8];
    #pragma unroll
    for (int j = 0; j < 8; ++j) ua[j] = 0.f;
    for (int d = 0; d < 32; ++d) {
        float wd = wz[d];
        #pragma unroll
        for (int j = 0; j < 8; ++j) ua[j] += wd * Pl[d][wv * 8 + j];
    }
    uint4 up;
    up.x = pk2(ua[0], ua[1]); up.y = pk2(ua[2], ua[3]);
    up.z = pk2(ua[4], ua[5]); up.w = pk2(ua[6], ua[7]);
    __hip_bfloat16* Up = Ubf + ((size_t)(b * NCHUNK + ck) * 64 + o) * 128 + h * 32 + wv * 8;
    *reinterpret_cast<uint4*>(Up) = up;
}

// y = U'(64x128) . vT^T via MFMA, direct-global fragments; fused bias + GN stats.
__global__ __launch_bounds__(256) void y_kernel(const __hip_bfloat16* __restrict__ qkv,
        const __hip_bfloat16* __restrict__ Ubf, const float* __restrict__ bout,
        float* __restrict__ y, float* __restrict__ stats) {
    int bx = blockIdx.x;   // 72 tiles of 128 positions
    int b  = blockIdx.y;   // 8
    int ck = bx >> 3;
    __shared__ float gsum[8], gsq[8];
    int t = threadIdx.x, w = t >> 6, l = t & 63;
    int l15 = l & 15, quad = l >> 4;
    if (t < 8) { gsum[t] = 0.f; gsq[t] = 0.f; }
    __syncthreads();
    const __hip_bfloat16* vt = qkv + 2 * SEC_SZ + (size_t)b * N_POS * 128;
    const __hip_bfloat16* Ub = Ubf + (size_t)(b * NCHUNK + ck) * 64 * 128;
    int nbase = bx * 128 + w * 32;
    f32x4 acc[4][2];
    #pragma unroll
    for (int mt = 0; mt < 4; ++mt) { acc[mt][0] = (f32x4){0,0,0,0}; acc[mt][1] = (f32x4){0,0,0,0}; }
    #pragma unroll
    for (int ks = 0; ks < 4; ++ks) {
        int k0 = ks * 32 + quad * 8;
        short8 bf[2];
        #pragma unroll
        for (int nt = 0; nt < 2; ++nt)
            bf[nt] = *reinterpret_cast<const short8*>(vt + (size_t)(nbase + nt * 16 + l15) * 128 + k0);
        #pragma unroll
        for (int mt = 0; mt < 4; ++mt) {
            short8 af = *reinterpret_cast<const short8*>(Ub + (size_t)(mt * 16 + l15) * 128 + k0);
            acc[mt][0] = __builtin_amdgcn_mfma_f32_16x16x32_bf16(af, bf[0], acc[mt][0], 0, 0, 0);
            acc[mt][1] = __builtin_amdgcn_mfma_f32_16x16x32_bf16(af, bf[1], acc[mt][1], 0, 0, 0);
        }
    }
    float gsl[4], gql[4];
    #pragma unroll
    for (int mt = 0; mt < 4; ++mt) { gsl[mt] = 0.f; gql[mt] = 0.f; }
    float* yb = y + (size_t)b * CDIM * N_POS;
    #pragma unroll
    for (int mt = 0; mt < 4; ++mt) {
        float4 bo = *reinterpret_cast<const float4*>(bout + mt * 16 + quad * 4);
        const float* bop = reinterpret_cast<const float*>(&bo);
        #pragma unroll
        for (int nt = 0; nt < 2; ++nt) {
            int n = nbase + nt * 16 + l15;
            #pragma unroll
            for (int r = 0; r < 4; ++r) {
                int o = mt * 16 + quad * 4 + r;
                float val = acc[mt][nt][r] + bop[r];
                yb[(size_t)o * N_POS + n] = val;
                gsl[mt] += val; gql[mt] += val * val;
            }
        }
    }
    #pragma unroll
    for (int off = 16; off >= 1; off >>= 1) {
        #pragma unroll
        for (int mt = 0; mt < 4; ++mt) {
            gsl[mt] += __shfl_xor(gsl[mt], off, 64);
            gql[mt] += __shfl_xor(gql[mt], off, 64);
        }
    }
    if (l == 0 || l == 32) {
        int qh = quad >> 1;
        #pragma unroll
        for (int mt = 0; mt < 4; ++mt) {
            atomicAdd(&gsum[2 * mt + qh], gsl[mt]);
            atomicAdd(&gsq[2 * mt + qh], gql[mt]);
        }
    }
    __syncthreads();
    if (t < 8) {
        atomicAdd(&stats[(b * 8 + t) * 2],     gsum[t]);
        atomicAdd(&stats[(b * 8 + t) * 2 + 1], gsq[t]);
    }
}

__global__ __launch_bounds__(256) void gn_kernel(float* __restrict__ y,
        const float* __restrict__ stats, const float* __restrict__ gamma,
        const float* __restrict__ beta) {
    int i4 = blockIdx.x * 256 + threadIdx.x;
    if (i4 >= (BATCH * CDIM * N_POS) / 4) return;
    int base = i4 * 4;
    int bc = base / N_POS;
    int c = bc & 63, b = bc >> 6;
    int g = c >> 3;
    float s = stats[(b * 8 + g) * 2], q = stats[(b * 8 + g) * 2 + 1];
    const float invN = 1.f / (8.f * N_POS);
    float mean = s * invN;
    float var = q * invN - mean * mean;
    float sc = rsqrtf(var + EPS);
    float ga = gamma[c] * sc;
    float be = beta[c] - mean * sc * gamma[c];
    float4 v = ((float4*)y)[i4];
    v.x = v.x * ga + be; v.y = v.y * ga + be; v.z = v.z * ga + be; v.w = v.w * ga + be;
    ((float4*)y)[i4] = v;
}

extern "C" void kernel_launch(void* const* d_in, const int* in_sizes, int n_in,
                              void* d_out, int out_size, void* d_ws, size_t ws_size,
                              hipStream_t stream) {
    const float* x     = (const float*)d_in[0];
    const float* Wqkv  = (const float*)d_in[1];
    const float* Wout  = (const float*)d_in[2];
    const float* bout  = (const float*)d_in[3];
    const float* gamma = (const float*)d_in[4];
    const float* beta  = (const float*)d_in[5];
    float* out = (float*)d_out;

    __hip_bfloat16* qkv = (__hip_bfloat16*)d_ws;
    float* stats  = (float*)((char*)d_ws + QKV_BYTES);
    float* Pparts = stats + 128;
    __hip_bfloat16* Ubf = (__hip_bfloat16*)(Pparts + 4 * PPART_SZ);

    qkv_kernel<<<dim3(36, 3, BATCH), 256, 0, stream>>>(x, Wqkv, qkv);
    smat_part<<<dim3(32, NCHUNK, 4), 256, 0, stream>>>(qkv, Pparts);
    umat_kernel<<<dim3(NCHUNK, BATCH, HEADS), 256, 0, stream>>>(Wout, Pparts, Ubf, stats);
    y_kernel<<<dim3(72, BATCH), 256, 0, stream>>>(qkv, Ubf, bout, out, stats);
    gn_kernel<<<dim3((BATCH * CDIM * N_POS / 4 + 255) / 256), 256, 0, stream>>>(out, stats, gamma, beta);
}

// Round 7
// 127.940 us; speedup vs baseline: 3.3580x; 1.0413x over previous
//
#include <hip/hip_runtime.h>
#include <hip/hip_bf16.h>

#define N_POS 9216
#define NCHUNK 9
#define CHUNKN 1024
#define BATCH 8
#define CDIM 64
#define HEADS 4
#define GROUPS 8
#define EPS 1e-5f

// ws layout: v bf16 [b][n][128] | stats fp32(128) | Pparts fp32 16x(32*9*1024) | U' bf16
#define VSEC_SZ ((size_t)BATCH * N_POS * 128)
#define VSEC_BYTES (VSEC_SZ * 2)
#define PPART_SZ ((size_t)32 * NCHUNK * 1024)   // floats per partial
#define NPART 16

typedef __attribute__((ext_vector_type(8))) short short8;
typedef __attribute__((ext_vector_type(4))) float f32x4;

static __device__ inline unsigned pk2(float a, float b) {
    __hip_bfloat162 h2(__float2bfloat16(a), __float2bfloat16(b));
    return *reinterpret_cast<unsigned*>(&h2);
}
static __device__ inline float bf2f(short s) {
    union { unsigned u; float f; } c; c.u = ((unsigned)(unsigned short)s) << 16; return c.f;
}

// Fused qk + P-partial. Grid (144, 8): 64 positions per block.
// Phase 1: q,k = Wqkv[0:256] @ x-tile (MFMA, M=256,N=64,K=64)
// Phase 2: transpose to channel-major LDS; k channel-softmax, exp(q) in place
// Phase 3: per-head P(32x32) MFMA over K=64 positions -> Pparts[pt]
__global__ __launch_bounds__(256) void qkp_kernel(const float* __restrict__ x,
        const float* __restrict__ Wqkv, float* __restrict__ Pparts) {
    int bx = blockIdx.x;            // 144
    int b  = blockIdx.y;
    int ck = bx >> 4, pt = bx & 15;
    int n0 = bx * 64;
    __shared__ __align__(16) char lraw[46080];
    __hip_bfloat16 (*xs)[72]  = (__hip_bfloat16(*)[72])lraw;            // [64][72]
    __hip_bfloat16 (*wsm)[72] = (__hip_bfloat16(*)[72])(lraw + 9216);   // [256][72]
    __hip_bfloat16 (*skT)[72] = (__hip_bfloat16(*)[72])lraw;            // [256][72] ch-major
    int t = threadIdx.x, w = t >> 6, l = t & 63;
    int l15 = l & 15, quad = l >> 4;

    // stage x: 4 threads per position, 16 channels each
    {
        int p = t & 63, cbase = (t >> 6) * 16;
        const float* xb = x + (size_t)b * CDIM * N_POS + n0 + p;
        #pragma unroll
        for (int j = 0; j < 16; j += 4) {
            float v0 = xb[(size_t)(cbase + j + 0) * N_POS];
            float v1 = xb[(size_t)(cbase + j + 1) * N_POS];
            float v2 = xb[(size_t)(cbase + j + 2) * N_POS];
            float v3 = xb[(size_t)(cbase + j + 3) * N_POS];
            uint2 u; u.x = pk2(v0, v1); u.y = pk2(v2, v3);
            *reinterpret_cast<uint2*>(&xs[p][cbase + j]) = u;
        }
    }
    // stage Wqkv rows 0..255 (q,k), coalesced: 16 float4 per thread
    {
        const float4* wr = (const float4*)Wqkv;
        #pragma unroll
        for (int j = 0; j < 16; ++j) {
            int f = t + j * 256;             // float4 index over 256x64 floats
            float4 v = wr[f];
            uint2 u; u.x = pk2(v.x, v.y); u.y = pk2(v.z, v.w);
            *reinterpret_cast<uint2*>(&wsm[f >> 4][(f & 15) * 4]) = u;
        }
    }
    __syncthreads();

    // qk MFMA: waves 0,1 -> q (rows 0..127); waves 2,3 -> k (rows 128..255)
    int mbase = (w >> 1) * 128;
    int nh = (w & 1) * 32;
    f32x4 acc[8][2];
    #pragma unroll
    for (int mt = 0; mt < 8; ++mt) { acc[mt][0] = (f32x4){0,0,0,0}; acc[mt][1] = (f32x4){0,0,0,0}; }
    #pragma unroll
    for (int ks = 0; ks < 2; ++ks) {
        int k0 = ks * 32 + quad * 8;
        short8 bfr[2];
        #pragma unroll
        for (int nt = 0; nt < 2; ++nt)
            bfr[nt] = *reinterpret_cast<const short8*>(&xs[nh + nt * 16 + l15][k0]);
        #pragma unroll
        for (int mt = 0; mt < 8; ++mt) {
            short8 afr = *reinterpret_cast<const short8*>(&wsm[mbase + mt * 16 + l15][k0]);
            acc[mt][0] = __builtin_amdgcn_mfma_f32_16x16x32_bf16(afr, bfr[0], acc[mt][0], 0, 0, 0);
            acc[mt][1] = __builtin_amdgcn_mfma_f32_16x16x32_bf16(afr, bfr[1], acc[mt][1], 0, 0, 0);
        }
    }
    __syncthreads();   // xs/wsm dead; reuse as skT

    // transpose to channel-major: skT[m][pos]
    #pragma unroll
    for (int mt = 0; mt < 8; ++mt)
        #pragma unroll
        for (int nt = 0; nt < 2; ++nt) {
            int p = nh + nt * 16 + l15;
            #pragma unroll
            for (int r = 0; r < 4; ++r)
                skT[mbase + mt * 16 + quad * 4 + r][p] = __float2bfloat16(acc[mt][nt][r]);
        }
    __syncthreads();

    // softmax: 1 task per thread: position p, head h
    {
        int p = t & 63, h = t >> 6;
        float kr[32]; float mx = -1e30f;
        #pragma unroll
        for (int d = 0; d < 32; ++d) { kr[d] = bf2f(*(const short*)&skT[128 + h * 32 + d][p]); mx = fmaxf(mx, kr[d]); }
        float s = 0.f;
        #pragma unroll
        for (int d = 0; d < 32; ++d) { kr[d] = __expf(kr[d] - mx); s += kr[d]; }
        float is = 1.f / s;
        #pragma unroll
        for (int d = 0; d < 32; ++d) skT[128 + h * 32 + d][p] = __float2bfloat16(kr[d] * is);
        #pragma unroll
        for (int d = 0; d < 32; ++d) {
            float qv = bf2f(*(const short*)&skT[h * 32 + d][p]);
            skT[h * 32 + d][p] = __float2bfloat16(__expf(qv));
        }
    }
    __syncthreads();

    // P MFMA: wave w = head w; A = exp(q) rows, B = ks rows; K = 64 positions
    f32x4 pac[2][2];
    pac[0][0] = (f32x4){0,0,0,0}; pac[0][1] = (f32x4){0,0,0,0};
    pac[1][0] = (f32x4){0,0,0,0}; pac[1][1] = (f32x4){0,0,0,0};
    #pragma unroll
    for (int step = 0; step < 2; ++step) {
        int k0 = step * 32 + quad * 8;
        short8 bk[2];
        #pragma unroll
        for (int nt = 0; nt < 2; ++nt)
            bk[nt] = *reinterpret_cast<const short8*>(&skT[128 + w * 32 + nt * 16 + l15][k0]);
        #pragma unroll
        for (int mt = 0; mt < 2; ++mt) {
            short8 aq = *reinterpret_cast<const short8*>(&skT[w * 32 + mt * 16 + l15][k0]);
            pac[mt][0] = __builtin_amdgcn_mfma_f32_16x16x32_bf16(aq, bk[0], pac[mt][0], 0, 0, 0);
            pac[mt][1] = __builtin_amdgcn_mfma_f32_16x16x32_bf16(aq, bk[1], pac[mt][1], 0, 0, 0);
        }
    }
    float* Pp = Pparts + (size_t)pt * PPART_SZ + ((size_t)(b * 4 + w) * NCHUNK + ck) * 1024;
    #pragma unroll
    for (int mt = 0; mt < 2; ++mt)
        #pragma unroll
        for (int nt = 0; nt < 2; ++nt)
            #pragma unroll
            for (int r = 0; r < 4; ++r)
                Pp[(mt * 16 + quad * 4 + r) * 32 + nt * 16 + l15] = pac[mt][nt][r];
}

// v = Wqkv[256:384] @ x, written position-major [n][128]. Grid (72, 8): 128 pos/block.
__global__ __launch_bounds__(256) void v_kernel(const float* __restrict__ x,
        const float* __restrict__ Wqkv, __hip_bfloat16* __restrict__ vsec) {
    int n0 = blockIdx.x * 128;
    int b  = blockIdx.y;
    __shared__ __align__(16) char lraw[36864];
    __hip_bfloat16 (*xs)[72]    = (__hip_bfloat16(*)[72])lraw;              // [128][72]
    __hip_bfloat16 (*wsm)[72]   = (__hip_bfloat16(*)[72])(lraw + 18432);    // [128][72]
    __hip_bfloat16 (*vbuf)[136] = (__hip_bfloat16(*)[136])lraw;             // [128][136]
    int t = threadIdx.x, w = t >> 6, l = t & 63;
    int l15 = l & 15, quad = l >> 4;

    {
        int p = t & 127, cbase = (t >> 7) * 32;
        const float* xb = x + (size_t)b * CDIM * N_POS + n0 + p;
        #pragma unroll
        for (int j = 0; j < 32; j += 4) {
            float v0 = xb[(size_t)(cbase + j + 0) * N_POS];
            float v1 = xb[(size_t)(cbase + j + 1) * N_POS];
            float v2 = xb[(size_t)(cbase + j + 2) * N_POS];
            float v3 = xb[(size_t)(cbase + j + 3) * N_POS];
            uint2 u; u.x = pk2(v0, v1); u.y = pk2(v2, v3);
            *reinterpret_cast<uint2*>(&xs[p][cbase + j]) = u;
        }
    }
    {
        const float4* wr = (const float4*)(Wqkv + 256 * CDIM);
        #pragma unroll
        for (int j = 0; j < 8; ++j) {
            int f = t + j * 256;             // over 128x64 floats
            float4 v = wr[f];
            uint2 u; u.x = pk2(v.x, v.y); u.y = pk2(v.z, v.w);
            *reinterpret_cast<uint2*>(&wsm[f >> 4][(f & 15) * 4]) = u;
        }
    }
    __syncthreads();

    int nw = w * 32;
    f32x4 acc[8][2];
    #pragma unroll
    for (int mt = 0; mt < 8; ++mt) { acc[mt][0] = (f32x4){0,0,0,0}; acc[mt][1] = (f32x4){0,0,0,0}; }
    #pragma unroll
    for (int ks = 0; ks < 2; ++ks) {
        int k0 = ks * 32 + quad * 8;
        short8 bfr[2];
        #pragma unroll
        for (int nt = 0; nt < 2; ++nt)
            bfr[nt] = *reinterpret_cast<const short8*>(&xs[nw + nt * 16 + l15][k0]);
        #pragma unroll
        for (int mt = 0; mt < 8; ++mt) {
            short8 afr = *reinterpret_cast<const short8*>(&wsm[mt * 16 + l15][k0]);
            acc[mt][0] = __builtin_amdgcn_mfma_f32_16x16x32_bf16(afr, bfr[0], acc[mt][0], 0, 0, 0);
            acc[mt][1] = __builtin_amdgcn_mfma_f32_16x16x32_bf16(afr, bfr[1], acc[mt][1], 0, 0, 0);
        }
    }
    __syncthreads();

    #pragma unroll
    for (int mt = 0; mt < 8; ++mt)
        #pragma unroll
        for (int nt = 0; nt < 2; ++nt) {
            int p = nw + nt * 16 + l15;
            uint2 u;
            u.x = pk2(acc[mt][nt][0], acc[mt][nt][1]);
            u.y = pk2(acc[mt][nt][2], acc[mt][nt][3]);
            *reinterpret_cast<uint2*>(&vbuf[p][mt * 16 + quad * 4]) = u;
        }
    __syncthreads();

    __hip_bfloat16* outb = vsec + ((size_t)b * N_POS + n0) * 128;
    int rg = t >> 4, c0 = (t & 15) * 8;
    #pragma unroll
    for (int j = 0; j < 8; ++j) {
        int r = j * 16 + rg;
        *reinterpret_cast<uint4*>(outb + (size_t)r * 128 + c0) =
            *reinterpret_cast<const uint4*>(&vbuf[r][c0]);
    }
}

// U'[o][h*32+dd] = sum_d Wout[o][h*32+d] * (1/Z_d) * P[d][dd];  Z_d = rowsum(P).
// Sums the 16 partials; also zeroes GN stats.
__global__ __launch_bounds__(256) void umat_kernel(const float* __restrict__ Wout,
        const float* __restrict__ Pparts, __hip_bfloat16* __restrict__ Ubf,
        float* __restrict__ stats) {
    int ck = blockIdx.x, b = blockIdx.y, h = blockIdx.z;
    int bh = b * 4 + h;
    int t = threadIdx.x;
    if (ck == 0 && h == 0 && t < 16) stats[b * 16 + t] = 0.f;
    __shared__ float Pl[32][32];
    __shared__ float iZ[32];
    size_t base4 = ((size_t)bh * NCHUNK + ck) * 256;
    {
        const float4* P0 = (const float4*)Pparts + base4 + t;
        float4 s = (float4){0.f, 0.f, 0.f, 0.f};
        #pragma unroll
        for (int j = 0; j < NPART; ++j) {
            float4 a = P0[j * (PPART_SZ / 4)];
            s.x += a.x; s.y += a.y; s.z += a.z; s.w += a.w;
        }
        ((float4*)Pl)[t] = s;
    }
    __syncthreads();
    if (t < 32) {
        float s = 0.f;
        #pragma unroll
        for (int c = 0; c < 32; ++c) s += Pl[t][c];
        iZ[t] = 1.f / s;
    }
    __syncthreads();
    int o = t & 63, wv = t >> 6;
    float wz[32];
    {
        const float4* wr = (const float4*)(Wout + (size_t)o * 128 + h * 32);
        #pragma unroll
        for (int j = 0; j < 8; ++j) {
            float4 f = wr[j];
            wz[j*4+0] = f.x * iZ[j*4+0]; wz[j*4+1] = f.y * iZ[j*4+1];
            wz[j*4+2] = f.z * iZ[j*4+2]; wz[j*4+3] = f.w * iZ[j*4+3];
        }
    }
    float ua[8];
    #pragma unroll
    for (int j = 0; j < 8; ++j) ua[j] = 0.f;
    for (int d = 0; d < 32; ++d) {
        float wd = wz[d];
        #pragma unroll
        for (int j = 0; j < 8; ++j) ua[j] += wd * Pl[d][wv * 8 + j];
    }
    uint4 up;
    up.x = pk2(ua[0], ua[1]); up.y = pk2(ua[2], ua[3]);
    up.z = pk2(ua[4], ua[5]); up.w = pk2(ua[6], ua[7]);
    __hip_bfloat16* Up = Ubf + ((size_t)(b * NCHUNK + ck) * 64 + o) * 128 + h * 32 + wv * 8;
    *reinterpret_cast<uint4*>(Up) = up;
}

// y = U'(64x128) . v^T via MFMA, direct-global fragments; fused bias + GN stats.
__global__ __launch_bounds__(256) void y_kernel(const __hip_bfloat16* __restrict__ vsec,
        const __hip_bfloat16* __restrict__ Ubf, const float* __restrict__ bout,
        float* __restrict__ y, float* __restrict__ stats) {
    int bx = blockIdx.x;   // 72 tiles of 128 positions
    int b  = blockIdx.y;   // 8
    int ck = bx >> 3;
    __shared__ float gsum[8], gsq[8];
    int t = threadIdx.x, w = t >> 6, l = t & 63;
    int l15 = l & 15, quad = l >> 4;
    if (t < 8) { gsum[t] = 0.f; gsq[t] = 0.f; }
    __syncthreads();
    const __hip_bfloat16* vt = vsec + (size_t)b * N_POS * 128;
    const __hip_bfloat16* Ub = Ubf + (size_t)(b * NCHUNK + ck) * 64 * 128;
    int nbase = bx * 128 + w * 32;
    f32x4 acc[4][2];
    #pragma unroll
    for (int mt = 0; mt < 4; ++mt) { acc[mt][0] = (f32x4){0,0,0,0}; acc[mt][1] = (f32x4){0,0,0,0}; }
    #pragma unroll
    for (int ks = 0; ks < 4; ++ks) {
        int k0 = ks * 32 + quad * 8;
        short8 bf[2];
        #pragma unroll
        for (int nt = 0; nt < 2; ++nt)
            bf[nt] = *reinterpret_cast<const short8*>(vt + (size_t)(nbase + nt * 16 + l15) * 128 + k0);
        #pragma unroll
        for (int mt = 0; mt < 4; ++mt) {
            short8 af = *reinterpret_cast<const short8*>(Ub + (size_t)(mt * 16 + l15) * 128 + k0);
            acc[mt][0] = __builtin_amdgcn_mfma_f32_16x16x32_bf16(af, bf[0], acc[mt][0], 0, 0, 0);
            acc[mt][1] = __builtin_amdgcn_mfma_f32_16x16x32_bf16(af, bf[1], acc[mt][1], 0, 0, 0);
        }
    }
    float gsl[4], gql[4];
    #pragma unroll
    for (int mt = 0; mt < 4; ++mt) { gsl[mt] = 0.f; gql[mt] = 0.f; }
    float* yb = y + (size_t)b * CDIM * N_POS;
    #pragma unroll
    for (int mt = 0; mt < 4; ++mt) {
        float4 bo = *reinterpret_cast<const float4*>(bout + mt * 16 + quad * 4);
        const float* bop = reinterpret_cast<const float*>(&bo);
        #pragma unroll
        for (int nt = 0; nt < 2; ++nt) {
            int n = nbase + nt * 16 + l15;
            #pragma unroll
            for (int r = 0; r < 4; ++r) {
                int o = mt * 16 + quad * 4 + r;
                float val = acc[mt][nt][r] + bop[r];
                yb[(size_t)o * N_POS + n] = val;
                gsl[mt] += val; gql[mt] += val * val;
            }
        }
    }
    #pragma unroll
    for (int off = 16; off >= 1; off >>= 1) {
        #pragma unroll
        for (int mt = 0; mt < 4; ++mt) {
            gsl[mt] += __shfl_xor(gsl[mt], off, 64);
            gql[mt] += __shfl_xor(gql[mt], off, 64);
        }
    }
    if (l == 0 || l == 32) {
        int qh = quad >> 1;
        #pragma unroll
        for (int mt = 0; mt < 4; ++mt) {
            atomicAdd(&gsum[2 * mt + qh], gsl[mt]);
            atomicAdd(&gsq[2 * mt + qh], gql[mt]);
        }
    }
    __syncthreads();
    if (t < 8) {
        atomicAdd(&stats[(b * 8 + t) * 2],     gsum[t]);
        atomicAdd(&stats[(b * 8 + t) * 2 + 1], gsq[t]);
    }
}

__global__ __launch_bounds__(256) void gn_kernel(float* __restrict__ y,
        const float* __restrict__ stats, const float* __restrict__ gamma,
        const float* __restrict__ beta) {
    int i4 = blockIdx.x * 256 + threadIdx.x;
    if (i4 >= (BATCH * CDIM * N_POS) / 4) return;
    int base = i4 * 4;
    int bc = base / N_POS;
    int c = bc & 63, b = bc >> 6;
    int g = c >> 3;
    float s = stats[(b * 8 + g) * 2], q = stats[(b * 8 + g) * 2 + 1];
    const float invN = 1.f / (8.f * N_POS);
    float mean = s * invN;
    float var = q * invN - mean * mean;
    float sc = rsqrtf(var + EPS);
    float ga = gamma[c] * sc;
    float be = beta[c] - mean * sc * gamma[c];
    float4 v = ((float4*)y)[i4];
    v.x = v.x * ga + be; v.y = v.y * ga + be; v.z = v.z * ga + be; v.w = v.w * ga + be;
    ((float4*)y)[i4] = v;
}

extern "C" void kernel_launch(void* const* d_in, const int* in_sizes, int n_in,
                              void* d_out, int out_size, void* d_ws, size_t ws_size,
                              hipStream_t stream) {
    const float* x     = (const float*)d_in[0];
    const float* Wqkv  = (const float*)d_in[1];
    const float* Wout  = (const float*)d_in[2];
    const float* bout  = (const float*)d_in[3];
    const float* gamma = (const float*)d_in[4];
    const float* beta  = (const float*)d_in[5];
    float* out = (float*)d_out;

    __hip_bfloat16* vsec = (__hip_bfloat16*)d_ws;
    float* stats  = (float*)((char*)d_ws + VSEC_BYTES);
    float* Pparts = stats + 128;
    __hip_bfloat16* Ubf = (__hip_bfloat16*)(Pparts + NPART * PPART_SZ);

    qkp_kernel<<<dim3(144, BATCH), 256, 0, stream>>>(x, Wqkv, Pparts);
    v_kernel<<<dim3(72, BATCH), 256, 0, stream>>>(x, Wqkv, vsec);
    umat_kernel<<<dim3(NCHUNK, BATCH, HEADS), 256, 0, stream>>>(Wout, Pparts, Ubf, stats);
    y_kernel<<<dim3(72, BATCH), 256, 0, stream>>>(vsec, Ubf, bout, out, stats);
    gn_kernel<<<dim3((BATCH * CDIM * N_POS / 4 + 255) / 256), 256, 0, stream>>>(out, stats, gamma, beta);
}